// Round 1
// baseline (1978.558 us; speedup 1.0000x reference)
//
#include <hip/hip_runtime.h>
#include <math.h>

#define NB 4
#define TT 1024
#define DD 1024
#define NTOK 4096        // NB*TT
#define ND (NTOK*DD)     // 4,194,304

// ---------- helpers ----------
__device__ __forceinline__ unsigned short f2bf(float f) {
    unsigned int b = __float_as_uint(f);
    b += 0x7fffu + ((b >> 16) & 1u);
    return (unsigned short)(b >> 16);
}
__device__ __forceinline__ float bf2f(unsigned short u) {
    return __uint_as_float(((unsigned int)u) << 16);
}

// ---------- k1: xmix = x + dxprev * maa_x ----------
__global__ __launch_bounds__(256) void k_mixx(const float* __restrict__ x,
                                              const float* __restrict__ maa_x,
                                              float* __restrict__ xmix) {
    int idx = blockIdx.x * 256 + threadIdx.x;   // grid 16384
    int d = idx & 1023;
    int t = (idx >> 10) & 1023;
    float xv = x[idx];
    float xm1 = (t > 0)    ? x[idx - 1024] : 0.f;
    float xp1 = (t < 1023) ? x[idx + 1024] : 0.f;
    float dx = 0.5f * (xm1 + xp1) - xv;
    xmix[idx] = xv + dx * maa_x[d];
}

// ---------- k2: xxx = tanh(xmix @ w1)  (4096x1024 @ 1024x160) ----------
__global__ __launch_bounds__(256) void k_xxx(const float* __restrict__ xmix,
                                             const float* __restrict__ w1,
                                             float* __restrict__ xxx) {
    __shared__ float xt[16][32];
    __shared__ float w1t[32][160];
    int tid = threadIdx.x;
    int tm = tid >> 4, tn = tid & 15;
    int tok0 = blockIdx.x * 16;     // grid 256
    float acc[10];
#pragma unroll
    for (int j = 0; j < 10; j++) acc[j] = 0.f;
    for (int kb = 0; kb < 1024; kb += 32) {
        __syncthreads();
#pragma unroll
        for (int i = 0; i < 2; i++) {
            int l = tid + i * 256;
            xt[l >> 5][l & 31] = xmix[(tok0 + (l >> 5)) * 1024 + kb + (l & 31)];
        }
#pragma unroll
        for (int i = 0; i < 20; i++) {
            int l = tid + i * 256;
            int row = l / 160, col = l % 160;
            w1t[row][col] = w1[(kb + row) * 160 + col];
        }
        __syncthreads();
#pragma unroll 8
        for (int kk = 0; kk < 32; kk++) {
            float a = xt[tm][kk];
#pragma unroll
            for (int j = 0; j < 10; j++)
                acc[j] = fmaf(a, w1t[kk][tn + 16 * j], acc[j]);
        }
    }
#pragma unroll
    for (int j = 0; j < 10; j++)
        xxx[(tok0 + tm) * 160 + tn + 16 * j] = tanhf(acc[j]);
}

// ---------- k3: mm einsum + five mixes ----------
__global__ __launch_bounds__(256) void k_mix5(const float* __restrict__ x,
                                              const float* __restrict__ xxx,
                                              const float* __restrict__ w2,
                                              const float* __restrict__ maa_w,
                                              const float* __restrict__ maa_k,
                                              const float* __restrict__ maa_v,
                                              const float* __restrict__ maa_r,
                                              const float* __restrict__ maa_g,
                                              float* __restrict__ xw, float* __restrict__ xk,
                                              float* __restrict__ xv, float* __restrict__ xr,
                                              float* __restrict__ xg) {
    __shared__ float xl[8][160];
    int tid = threadIdx.x;
    int tok0 = blockIdx.x * 8;      // grid 512
#pragma unroll
    for (int i = 0; i < 5; i++) {
        int l = tid + i * 256;
        xl[l / 160][l % 160] = xxx[tok0 * 160 + l];
    }
    __syncthreads();
#pragma unroll 1
    for (int c = 0; c < 4; c++) {
        int d = c * 256 + tid;
        float acc[5][8];
#pragma unroll
        for (int f = 0; f < 5; f++)
#pragma unroll
            for (int g = 0; g < 8; g++) acc[f][g] = 0.f;
#pragma unroll
        for (int f = 0; f < 5; f++) {
#pragma unroll 8
            for (int m = 0; m < 32; m++) {
                float wv = w2[(f * 32 + m) * 1024 + d];
#pragma unroll
                for (int g = 0; g < 8; g++)
                    acc[f][g] = fmaf(xl[g][f * 32 + m], wv, acc[f][g]);
            }
        }
        float maas[5] = {maa_w[d], maa_k[d], maa_v[d], maa_r[d], maa_g[d]};
#pragma unroll
        for (int g = 0; g < 8; g++) {
            int tok = tok0 + g;
            int t = tok & 1023;
            float xv_ = x[tok * 1024 + d];
            float xm1 = (t > 0)    ? x[(tok - 1) * 1024 + d] : 0.f;
            float xp1 = (t < 1023) ? x[(tok + 1) * 1024 + d] : 0.f;
            float dx = 0.5f * (xm1 + xp1) - xv_;
            xw[tok * 1024 + d] = xv_ + dx * (maas[0] + acc[0][g]);
            xk[tok * 1024 + d] = xv_ + dx * (maas[1] + acc[1][g]);
            xv[tok * 1024 + d] = xv_ + dx * (maas[2] + acc[2][g]);
            xr[tok * 1024 + d] = xv_ + dx * (maas[3] + acc[3][g]);
            xg[tok * 1024 + d] = xv_ + dx * (maas[4] + acc[4][g]);
        }
    }
}

// ---------- k4: C[4096][1024] = A[4096][1024] @ W[1024][1024]^T, 128x128 tile ----------
__global__ __launch_bounds__(256) void k_gemm_nt(const float* __restrict__ A,
                                                 const float* __restrict__ W,
                                                 float* __restrict__ C, int act) {
    __shared__ float At[16][136];
    __shared__ float Bt[16][136];
    int tid = threadIdx.x;
    int tm = tid >> 4, tn = tid & 15;
    int m0 = (blockIdx.x >> 3) * 128;   // grid 256 = 32 x 8
    int n0 = (blockIdx.x & 7) * 128;
    float acc[2][2][4][4] = {};
    for (int kb = 0; kb < 1024; kb += 16) {
        __syncthreads();
#pragma unroll
        for (int i = 0; i < 2; i++) {
            int l = tid + i * 256;
            int row = l >> 2, k4 = l & 3;
            float4 va = *(const float4*)&A[(m0 + row) * 1024 + kb + k4 * 4];
            At[k4 * 4 + 0][row] = va.x; At[k4 * 4 + 1][row] = va.y;
            At[k4 * 4 + 2][row] = va.z; At[k4 * 4 + 3][row] = va.w;
        }
#pragma unroll
        for (int i = 0; i < 2; i++) {
            int l = tid + i * 256;
            int row = l >> 2, k4 = l & 3;
            float4 vb = *(const float4*)&W[(n0 + row) * 1024 + kb + k4 * 4];
            Bt[k4 * 4 + 0][row] = vb.x; Bt[k4 * 4 + 1][row] = vb.y;
            Bt[k4 * 4 + 2][row] = vb.z; Bt[k4 * 4 + 3][row] = vb.w;
        }
        __syncthreads();
#pragma unroll
        for (int kk = 0; kk < 16; kk++) {
            float4 a0 = *(const float4*)&At[kk][tm * 4];
            float4 a1 = *(const float4*)&At[kk][tm * 4 + 64];
            float4 b0 = *(const float4*)&Bt[kk][tn * 4];
            float4 b1 = *(const float4*)&Bt[kk][tn * 4 + 64];
            const float* ap[2] = {(const float*)&a0, (const float*)&a1};
            const float* bp[2] = {(const float*)&b0, (const float*)&b1};
#pragma unroll
            for (int ar = 0; ar < 2; ar++)
#pragma unroll
                for (int br = 0; br < 2; br++)
#pragma unroll
                    for (int ca = 0; ca < 4; ca++)
#pragma unroll
                        for (int cb = 0; cb < 4; cb++)
                            acc[ar][br][ca][cb] = fmaf(ap[ar][ca], bp[br][cb], acc[ar][br][ca][cb]);
        }
    }
#pragma unroll
    for (int ar = 0; ar < 2; ar++)
#pragma unroll
        for (int ca = 0; ca < 4; ca++) {
            int m = m0 + ar * 64 + tm * 4 + ca;
#pragma unroll
            for (int br = 0; br < 2; br++) {
                float4 o;
                o.x = acc[ar][br][ca][0]; o.y = acc[ar][br][ca][1];
                o.z = acc[ar][br][ca][2]; o.w = acc[ar][br][ca][3];
                if (act == 1) {   // silu
                    o.x = o.x / (1.f + expf(-o.x));
                    o.y = o.y / (1.f + expf(-o.y));
                    o.z = o.z / (1.f + expf(-o.z));
                    o.w = o.w / (1.f + expf(-o.w));
                }
                *(float4*)&C[m * 1024 + n0 + br * 64 + tn * 4] = o;
            }
        }
}

// ---------- decay GEMM1: dech = tanh(xw @ dw1)  (4096x1024 @ 1024x64) ----------
__global__ __launch_bounds__(256) void k_dec1(const float* __restrict__ xw,
                                              const float* __restrict__ dw1,
                                              float* __restrict__ dech) {
    __shared__ float xt[16][68];
    __shared__ float wt[16][68];
    int tid = threadIdx.x;
    int tm = tid >> 4, tn = tid & 15;
    int tok0 = blockIdx.x * 64;    // grid 64
    float acc[4][4] = {};
    for (int kb = 0; kb < 1024; kb += 16) {
        __syncthreads();
        {
            int row = tid >> 2, k4 = tid & 3;
            float4 va = *(const float4*)&xw[(tok0 + row) * 1024 + kb + k4 * 4];
            xt[k4 * 4 + 0][row] = va.x; xt[k4 * 4 + 1][row] = va.y;
            xt[k4 * 4 + 2][row] = va.z; xt[k4 * 4 + 3][row] = va.w;
        }
        {
            int kk = tid >> 4, j4 = tid & 15;
            float4 vb = *(const float4*)&dw1[(kb + kk) * 64 + j4 * 4];
            *(float4*)&wt[kk][j4 * 4] = vb;
        }
        __syncthreads();
#pragma unroll
        for (int kk = 0; kk < 16; kk++) {
            float4 a = *(const float4*)&xt[kk][tm * 4];
            float4 b = *(const float4*)&wt[kk][tn * 4];
            const float* ap = (const float*)&a;
            const float* bp = (const float*)&b;
#pragma unroll
            for (int ca = 0; ca < 4; ca++)
#pragma unroll
                for (int cb = 0; cb < 4; cb++)
                    acc[ca][cb] = fmaf(ap[ca], bp[cb], acc[ca][cb]);
        }
    }
#pragma unroll
    for (int ca = 0; ca < 4; ca++) {
        float4 o;
        o.x = tanhf(acc[ca][0]); o.y = tanhf(acc[ca][1]);
        o.z = tanhf(acc[ca][2]); o.w = tanhf(acc[ca][3]);
        *(float4*)&dech[(tok0 + tm * 4 + ca) * 64 + tn * 4] = o;
    }
}

// ---------- decay GEMM2: wdec = time_decay + dech @ dw2  (4096x64 @ 64x1024) ----------
__global__ __launch_bounds__(256) void k_dec2(const float* __restrict__ dech,
                                              const float* __restrict__ dw2,
                                              const float* __restrict__ tdec,
                                              float* __restrict__ wdec) {
    __shared__ float hl[8][64];
    int tid = threadIdx.x;
    int tok0 = blockIdx.x * 8;     // grid 512
    {
        int l = tid;        hl[l >> 6][l & 63] = dech[tok0 * 64 + l];
        l = tid + 256;      hl[l >> 6][l & 63] = dech[tok0 * 64 + l];
    }
    __syncthreads();
#pragma unroll 1
    for (int c = 0; c < 4; c++) {
        int d = c * 256 + tid;
        float acc[8] = {};
#pragma unroll 8
        for (int j = 0; j < 64; j++) {
            float wv = dw2[j * 1024 + d];
#pragma unroll
            for (int g = 0; g < 8; g++) acc[g] = fmaf(hl[g][j], wv, acc[g]);
        }
        float td = tdec[d];
#pragma unroll
        for (int g = 0; g < 8; g++) wdec[(tok0 + g) * 1024 + d] = td + acc[g];
    }
}

// ---------- k5: scan (cumsum of -exp(w)) + clipped cf/cb ----------
__global__ __launch_bounds__(64) void k_scan(float* __restrict__ wdec,
                                             float* __restrict__ cf,
                                             float* __restrict__ cb) {
    int b = blockIdx.x >> 4;                    // grid 64 = 4 b x 16 dchunks
    int d = (blockIdx.x & 15) * 64 + threadIdx.x;
    const int base = b * 1024 * 1024 + d;
    float cum = 0.f, sf = 0.f, sb = 0.f;
#pragma unroll 4
    for (int t = 0; t < 1024; t++) {
        int idx = base + t * 1024;
        float wv = wdec[idx];
        cum += -expf(wv);
        wdec[idx] = cum;
        if (t == 511) sb = cum;
        if (t == 512) sf = cum;
    }
    float prev = 0.f;
#pragma unroll 4
    for (int t = 0; t < 1024; t++) {
        int idx = base + t * 1024;
        float cs = wdec[idx];
        cf[idx] = fminf(fmaxf(cs - sf, -60.f), 60.f);
        cb[idx] = fminf(fmaxf(prev - sb, -60.f), 60.f);
        prev = cs;
    }
}

// ---------- k6: bidirectional LION attention ----------
__global__ __launch_bounds__(256) void k_attn(const float* __restrict__ r,
                                              const float* __restrict__ k,
                                              const float* __restrict__ v,
                                              const float* __restrict__ cf,
                                              const float* __restrict__ cb,
                                              float* __restrict__ y) {
    __shared__ float qt[64][68];
    __shared__ float kt[64][68];
    __shared__ unsigned short vt[64][64];
    __shared__ float St[64][68];
    int tid = threadIdx.x;
    int tm = tid >> 4, tn = tid & 15;
    int bh = blockIdx.x >> 4;       // grid 1024 = 64 (b,h) x 16 i-tiles
    int it = blockIdx.x & 15;
    int b = bh >> 4, h = bh & 15;
    int i0 = it * 64;
    int bt0 = b * 1024;
    int col0 = h * 64;
    float4 yacc[4];
#pragma unroll
    for (int im = 0; im < 4; im++) yacc[im] = make_float4(0.f, 0.f, 0.f, 0.f);

    for (int phase = 0; phase < 2; phase++) {
        __syncthreads();
        // stage q tile: qf = r*exp(cf)  |  qb = r*exp(-cb)
#pragma unroll
        for (int i = 0; i < 4; i++) {
            int l = tid + i * 256;
            int row = l >> 4, k4 = l & 15;
            int ga = (bt0 + i0 + row) * 1024 + col0 + k4 * 4;
            float4 rv = *(const float4*)&r[ga];
            float4 cv = (phase == 0) ? *(const float4*)&cf[ga] : *(const float4*)&cb[ga];
            float sgn = (phase == 0) ? 1.f : -1.f;
            qt[row][k4 * 4 + 0] = rv.x * expf(sgn * cv.x);
            qt[row][k4 * 4 + 1] = rv.y * expf(sgn * cv.y);
            qt[row][k4 * 4 + 2] = rv.z * expf(sgn * cv.z);
            qt[row][k4 * 4 + 3] = rv.w * expf(sgn * cv.w);
        }
        int jt_lo = (phase == 0) ? 0 : it;
        int jt_hi = (phase == 0) ? it : 15;
        for (int jt = jt_lo; jt <= jt_hi; jt++) {
            __syncthreads();
            // stage k tile: kf = k*exp(-cf) | kb = k*exp(cb) ; v tile as bf16
#pragma unroll
            for (int i = 0; i < 4; i++) {
                int l = tid + i * 256;
                int row = l >> 4, k4 = l & 15;
                int ga = (bt0 + jt * 64 + row) * 1024 + col0 + k4 * 4;
                float4 kv = *(const float4*)&k[ga];
                float4 cv = (phase == 0) ? *(const float4*)&cf[ga] : *(const float4*)&cb[ga];
                float sgn = (phase == 0) ? -1.f : 1.f;
                kt[row][k4 * 4 + 0] = kv.x * expf(sgn * cv.x);
                kt[row][k4 * 4 + 1] = kv.y * expf(sgn * cv.y);
                kt[row][k4 * 4 + 2] = kv.z * expf(sgn * cv.z);
                kt[row][k4 * 4 + 3] = kv.w * expf(sgn * cv.w);
                float4 vv = *(const float4*)&v[ga];
                vt[row][k4 * 4 + 0] = f2bf(vv.x);
                vt[row][k4 * 4 + 1] = f2bf(vv.y);
                vt[row][k4 * 4 + 2] = f2bf(vv.z);
                vt[row][k4 * 4 + 3] = f2bf(vv.w);
            }
            __syncthreads();
            bool isdiag = (jt == it);
            float S[4][4] = {};
#pragma unroll
            for (int kk4 = 0; kk4 < 16; kk4++) {
                float4 a[4], bb[4];
#pragma unroll
                for (int im = 0; im < 4; im++)
                    a[im] = *(const float4*)&qt[tm + 16 * im][kk4 * 4];
#pragma unroll
                for (int jn = 0; jn < 4; jn++)
                    bb[jn] = *(const float4*)&kt[tn + 16 * jn][kk4 * 4];
#pragma unroll
                for (int im = 0; im < 4; im++)
#pragma unroll
                    for (int jn = 0; jn < 4; jn++) {
                        S[im][jn] = fmaf(a[im].x, bb[jn].x, S[im][jn]);
                        S[im][jn] = fmaf(a[im].y, bb[jn].y, S[im][jn]);
                        S[im][jn] = fmaf(a[im].z, bb[jn].z, S[im][jn]);
                        S[im][jn] = fmaf(a[im].w, bb[jn].w, S[im][jn]);
                    }
            }
#pragma unroll
            for (int im = 0; im < 4; im++)
#pragma unroll
                for (int jn = 0; jn < 4; jn++) {
                    int i = tm + 16 * im, j = tn + 16 * jn;
                    float sv = S[im][jn];
                    if (isdiag) {
                        bool keep = (phase == 0) ? (i >= j) : (i < j);
                        sv = keep ? sv : 0.f;
                    }
                    St[i][j] = sv;
                }
            __syncthreads();
            // stage2: y += St @ vt
#pragma unroll
            for (int jj4 = 0; jj4 < 16; jj4++) {
                float4 s4[4];
#pragma unroll
                for (int im = 0; im < 4; im++)
                    s4[im] = *(const float4*)&St[tm + 16 * im][jj4 * 4];
#pragma unroll
                for (int c = 0; c < 4; c++) {
                    uint2 u = *(const uint2*)&vt[jj4 * 4 + c][tn * 4];
                    float v0 = __uint_as_float(u.x << 16);
                    float v1 = __uint_as_float(u.x & 0xffff0000u);
                    float v2 = __uint_as_float(u.y << 16);
                    float v3 = __uint_as_float(u.y & 0xffff0000u);
#pragma unroll
                    for (int im = 0; im < 4; im++) {
                        float sc = ((const float*)&s4[im])[c];
                        yacc[im].x = fmaf(sc, v0, yacc[im].x);
                        yacc[im].y = fmaf(sc, v1, yacc[im].y);
                        yacc[im].z = fmaf(sc, v2, yacc[im].z);
                        yacc[im].w = fmaf(sc, v3, yacc[im].w);
                    }
                }
            }
        }
    }
#pragma unroll
    for (int im = 0; im < 4; im++)
        *(float4*)&y[(bt0 + i0 + tm + 16 * im) * 1024 + col0 + tn * 4] = yacc[im];
}

// ---------- k7a: groupnorm over K=64 per head, * ln_w + ln_b, * g ----------
__global__ __launch_bounds__(256) void k_gn(const float* __restrict__ y,
                                            const float* __restrict__ g,
                                            const float* __restrict__ lnw,
                                            const float* __restrict__ lnb,
                                            float* __restrict__ z) {
    int tid = threadIdx.x;
    int lane = tid & 63;
    int wv = tid >> 6;
    int group = blockIdx.x * 4 + wv;     // grid 16384 -> 65536 groups
    int tok = group >> 4, h = group & 15;
    int d = h * 64 + lane;
    float val = y[tok * 1024 + d];
    float s = val, s2 = val * val;
#pragma unroll
    for (int off = 32; off > 0; off >>= 1) {
        s  += __shfl_xor(s, off, 64);
        s2 += __shfl_xor(s2, off, 64);
    }
    float mu = s * (1.f / 64.f);
    float var = s2 * (1.f / 64.f) - mu * mu;
    float inv = rsqrtf(var + 6.4e-4f);
    float yn = (val - mu) * inv * lnw[d] + lnb[d];
    z[tok * 1024 + d] = yn * g[tok * 1024 + d];
}

extern "C" void kernel_launch(void* const* d_in, const int* in_sizes, int n_in,
                              void* d_out, int out_size, void* d_ws, size_t ws_size,
                              hipStream_t stream) {
    const float* x     = (const float*)d_in[0];
    const float* maa_x = (const float*)d_in[1];
    const float* maa_w = (const float*)d_in[2];
    const float* maa_k = (const float*)d_in[3];
    const float* maa_v = (const float*)d_in[4];
    const float* maa_r = (const float*)d_in[5];
    const float* maa_g = (const float*)d_in[6];
    const float* w1    = (const float*)d_in[7];
    const float* w2    = (const float*)d_in[8];
    const float* tdec  = (const float*)d_in[9];
    const float* dw1   = (const float*)d_in[10];
    const float* dw2   = (const float*)d_in[11];
    const float* W_r   = (const float*)d_in[12];
    const float* W_k   = (const float*)d_in[13];
    const float* W_v   = (const float*)d_in[14];
    const float* W_g   = (const float*)d_in[15];
    const float* W_o   = (const float*)d_in[16];
    const float* lnw   = (const float*)d_in[17];
    const float* lnb   = (const float*)d_in[18];

    float* ws   = (float*)d_ws;
    float* xmix = ws;
    float* xxx  = xmix + ND;
    float* dech = xxx + NTOK * 160;
    float* xw   = dech + NTOK * 64;
    float* xk   = xw + ND;
    float* xv   = xk + ND;
    float* xr   = xv + ND;
    float* xg   = xr + ND;
    float* rr   = xg + ND;
    float* kk   = rr + ND;
    float* vv   = kk + ND;
    float* gg   = vv + ND;
    float* wdec = gg + ND;
    // reuse (stream-ordered safe):
    float* cfb = xk;    // after k-proj GEMM consumed xk
    float* cbb = xv;    // after v-proj GEMM consumed xv
    float* yb  = xg;    // after g-proj GEMM consumed xg
    float* zb  = xmix;  // after k_xxx consumed xmix

    k_mixx<<<16384, 256, 0, stream>>>(x, maa_x, xmix);
    k_xxx<<<256, 256, 0, stream>>>(xmix, w1, xxx);
    k_mix5<<<512, 256, 0, stream>>>(x, xxx, w2, maa_w, maa_k, maa_v, maa_r, maa_g,
                                    xw, xk, xv, xr, xg);
    k_gemm_nt<<<256, 256, 0, stream>>>(xr, W_r, rr, 0);
    k_gemm_nt<<<256, 256, 0, stream>>>(xk, W_k, kk, 0);
    k_gemm_nt<<<256, 256, 0, stream>>>(xv, W_v, vv, 0);
    k_gemm_nt<<<256, 256, 0, stream>>>(xg, W_g, gg, 1);
    k_dec1<<<64, 256, 0, stream>>>(xw, dw1, dech);
    k_dec2<<<512, 256, 0, stream>>>(dech, dw2, tdec, wdec);
    k_scan<<<64, 64, 0, stream>>>(wdec, cfb, cbb);
    k_attn<<<1024, 256, 0, stream>>>(rr, kk, vv, cfb, cbb, yb);
    k_gn<<<16384, 256, 0, stream>>>(yb, gg, lnw, lnb, zb);
    k_gemm_nt<<<256, 256, 0, stream>>>(zb, W_o, (float*)d_out, 0);
}

// Round 2
// 994.683 us; speedup vs baseline: 1.9891x; 1.9891x over previous
//
#include <hip/hip_runtime.h>
#include <math.h>

#define NB 4
#define TT 1024
#define DD 1024
#define NTOK 4096
#define ND (NTOK*DD)

typedef __attribute__((ext_vector_type(8))) short bh8;
typedef __attribute__((ext_vector_type(4))) float fx4;

__device__ __forceinline__ unsigned short f2bf(float f) {
    unsigned int b = __float_as_uint(f);
    b += 0x7fffu + ((b >> 16) & 1u);
    return (unsigned short)(b >> 16);
}

// ---------- weight fp32 -> bf16 ----------
__global__ __launch_bounds__(256) void k_wconv(const float* __restrict__ s0, const float* __restrict__ s1,
                                               const float* __restrict__ s2, const float* __restrict__ s3,
                                               const float* __restrict__ s4,
                                               unsigned short* __restrict__ d0, unsigned short* __restrict__ d1,
                                               unsigned short* __restrict__ d2, unsigned short* __restrict__ d3,
                                               unsigned short* __restrict__ d4) {
    const float* s; unsigned short* d;
    switch (blockIdx.y) {
        case 0: s = s0; d = d0; break;
        case 1: s = s1; d = d1; break;
        case 2: s = s2; d = d2; break;
        case 3: s = s3; d = d3; break;
        default: s = s4; d = d4; break;
    }
    int i = (blockIdx.x * 256 + threadIdx.x) * 8;   // grid (512,5)
    float4 a = *(const float4*)(s + i);
    float4 b = *(const float4*)(s + i + 4);
    uint4 o;
    o.x = ((unsigned)f2bf(a.y) << 16) | f2bf(a.x);
    o.y = ((unsigned)f2bf(a.w) << 16) | f2bf(a.z);
    o.z = ((unsigned)f2bf(b.y) << 16) | f2bf(b.x);
    o.w = ((unsigned)f2bf(b.w) << 16) | f2bf(b.z);
    *(uint4*)(d + i) = o;
}

// ---------- k1: xmix = x + dxprev * maa_x ----------
__global__ __launch_bounds__(256) void k_mixx(const float* __restrict__ x,
                                              const float* __restrict__ maa_x,
                                              float* __restrict__ xmix) {
    int idx = blockIdx.x * 256 + threadIdx.x;   // grid 16384
    int d = idx & 1023;
    int t = (idx >> 10) & 1023;
    float xv = x[idx];
    float xm1 = (t > 0)    ? x[idx - 1024] : 0.f;
    float xp1 = (t < 1023) ? x[idx + 1024] : 0.f;
    float dx = 0.5f * (xm1 + xp1) - xv;
    xmix[idx] = xv + dx * maa_x[d];
}

// ---------- k2: xxx = tanh(xmix @ w1) ----------
__global__ __launch_bounds__(256) void k_xxx(const float* __restrict__ xmix,
                                             const float* __restrict__ w1,
                                             float* __restrict__ xxx) {
    __shared__ float xt[16][32];
    __shared__ float w1t[32][160];
    int tid = threadIdx.x;
    int tm = tid >> 4, tn = tid & 15;
    int tok0 = blockIdx.x * 16;     // grid 256
    float acc[10];
#pragma unroll
    for (int j = 0; j < 10; j++) acc[j] = 0.f;
    for (int kb = 0; kb < 1024; kb += 32) {
        __syncthreads();
#pragma unroll
        for (int i = 0; i < 2; i++) {
            int l = tid + i * 256;
            xt[l >> 5][l & 31] = xmix[(tok0 + (l >> 5)) * 1024 + kb + (l & 31)];
        }
#pragma unroll
        for (int i = 0; i < 20; i++) {
            int l = tid + i * 256;
            int row = l / 160, col = l % 160;
            w1t[row][col] = w1[(kb + row) * 160 + col];
        }
        __syncthreads();
#pragma unroll 8
        for (int kk = 0; kk < 32; kk++) {
            float a = xt[tm][kk];
#pragma unroll
            for (int j = 0; j < 10; j++)
                acc[j] = fmaf(a, w1t[kk][tn + 16 * j], acc[j]);
        }
    }
#pragma unroll
    for (int j = 0; j < 10; j++)
        xxx[(tok0 + tm) * 160 + tn + 16 * j] = tanhf(acc[j]);
}

// ---------- k3: mm einsum + five mixes (bf16 outs for MFMA GEMMs) ----------
__global__ __launch_bounds__(256) void k_mix5(const float* __restrict__ x,
                                              const float* __restrict__ xxx,
                                              const float* __restrict__ w2,
                                              const float* __restrict__ maa_w,
                                              const float* __restrict__ maa_k,
                                              const float* __restrict__ maa_v,
                                              const float* __restrict__ maa_r,
                                              const float* __restrict__ maa_g,
                                              float* __restrict__ xw,
                                              unsigned short* __restrict__ xk16,
                                              unsigned short* __restrict__ xv16,
                                              unsigned short* __restrict__ xr16,
                                              unsigned short* __restrict__ xg16) {
    __shared__ float xl[8][160];
    int tid = threadIdx.x;
    int tok0 = blockIdx.x * 8;      // grid 512
#pragma unroll
    for (int i = 0; i < 5; i++) {
        int l = tid + i * 256;
        xl[l / 160][l % 160] = xxx[tok0 * 160 + l];
    }
    __syncthreads();
#pragma unroll 1
    for (int c = 0; c < 4; c++) {
        int d = c * 256 + tid;
        float acc[5][8];
#pragma unroll
        for (int f = 0; f < 5; f++)
#pragma unroll
            for (int g = 0; g < 8; g++) acc[f][g] = 0.f;
#pragma unroll
        for (int f = 0; f < 5; f++) {
#pragma unroll 8
            for (int m = 0; m < 32; m++) {
                float wv = w2[(f * 32 + m) * 1024 + d];
#pragma unroll
                for (int g = 0; g < 8; g++)
                    acc[f][g] = fmaf(xl[g][f * 32 + m], wv, acc[f][g]);
            }
        }
        float maas[5] = {maa_w[d], maa_k[d], maa_v[d], maa_r[d], maa_g[d]};
#pragma unroll
        for (int g = 0; g < 8; g++) {
            int tok = tok0 + g;
            int t = tok & 1023;
            float xin = x[tok * 1024 + d];
            float xm1 = (t > 0)    ? x[(tok - 1) * 1024 + d] : 0.f;
            float xp1 = (t < 1023) ? x[(tok + 1) * 1024 + d] : 0.f;
            float dx = 0.5f * (xm1 + xp1) - xin;
            xw[tok * 1024 + d]   = xin + dx * (maas[0] + acc[0][g]);
            xk16[tok * 1024 + d] = f2bf(xin + dx * (maas[1] + acc[1][g]));
            xv16[tok * 1024 + d] = f2bf(xin + dx * (maas[2] + acc[2][g]));
            xr16[tok * 1024 + d] = f2bf(xin + dx * (maas[3] + acc[3][g]));
            xg16[tok * 1024 + d] = f2bf(xin + dx * (maas[4] + acc[4][g]));
        }
    }
}

// ---------- decay GEMM1: dech = tanh(xw @ dw1) ----------
__global__ __launch_bounds__(256) void k_dec1(const float* __restrict__ xw,
                                              const float* __restrict__ dw1,
                                              float* __restrict__ dech) {
    __shared__ float xt[16][68];
    __shared__ float wt[16][68];
    int tid = threadIdx.x;
    int tm = tid >> 4, tn = tid & 15;
    int tok0 = blockIdx.x * 64;    // grid 64
    float acc[4][4] = {};
    for (int kb = 0; kb < 1024; kb += 16) {
        __syncthreads();
        {
            int row = tid >> 2, k4 = tid & 3;
            float4 va = *(const float4*)&xw[(tok0 + row) * 1024 + kb + k4 * 4];
            xt[k4 * 4 + 0][row] = va.x; xt[k4 * 4 + 1][row] = va.y;
            xt[k4 * 4 + 2][row] = va.z; xt[k4 * 4 + 3][row] = va.w;
        }
        {
            int kk = tid >> 4, j4 = tid & 15;
            float4 vb = *(const float4*)&dw1[(kb + kk) * 64 + j4 * 4];
            *(float4*)&wt[kk][j4 * 4] = vb;
        }
        __syncthreads();
#pragma unroll
        for (int kk = 0; kk < 16; kk++) {
            float4 a = *(const float4*)&xt[kk][tm * 4];
            float4 b = *(const float4*)&wt[kk][tn * 4];
            const float* ap = (const float*)&a;
            const float* bp = (const float*)&b;
#pragma unroll
            for (int ca = 0; ca < 4; ca++)
#pragma unroll
                for (int cb = 0; cb < 4; cb++)
                    acc[ca][cb] = fmaf(ap[ca], bp[cb], acc[ca][cb]);
        }
    }
#pragma unroll
    for (int ca = 0; ca < 4; ca++) {
        float4 o;
        o.x = tanhf(acc[ca][0]); o.y = tanhf(acc[ca][1]);
        o.z = tanhf(acc[ca][2]); o.w = tanhf(acc[ca][3]);
        *(float4*)&dech[(tok0 + tm * 4 + ca) * 64 + tn * 4] = o;
    }
}

// ---------- decay GEMM2: ew = -exp(time_decay + dech @ dw2) ----------
__global__ __launch_bounds__(256) void k_dec2(const float* __restrict__ dech,
                                              const float* __restrict__ dw2,
                                              const float* __restrict__ tdec,
                                              float* __restrict__ ew) {
    __shared__ float hl[8][64];
    int tid = threadIdx.x;
    int tok0 = blockIdx.x * 8;     // grid 512
    {
        int l = tid;        hl[l >> 6][l & 63] = dech[tok0 * 64 + l];
        l = tid + 256;      hl[l >> 6][l & 63] = dech[tok0 * 64 + l];
    }
    __syncthreads();
#pragma unroll 1
    for (int c = 0; c < 4; c++) {
        int d = c * 256 + tid;
        float acc[8] = {};
#pragma unroll 8
        for (int j = 0; j < 64; j++) {
            float wv = dw2[j * 1024 + d];
#pragma unroll
            for (int g = 0; g < 8; g++) acc[g] = fmaf(hl[g][j], wv, acc[g]);
        }
        float td = tdec[d];
#pragma unroll
        for (int g = 0; g < 8; g++) ew[(tok0 + g) * 1024 + d] = -expf(td + acc[g]);
    }
}

// ---------- scan stage 1: per-segment sums ----------
__global__ __launch_bounds__(64) void k_scan1(const float* __restrict__ ew, float* __restrict__ segsum) {
    int bx = blockIdx.x;            // grid 1024 = 4b x 16seg x 16dch
    int b = bx >> 8, seg = (bx >> 4) & 15, dch = bx & 15;
    int d = dch * 64 + threadIdx.x;
    size_t base = ((size_t)(b * 1024 + seg * 64)) * 1024 + d;
    float s = 0.f;
#pragma unroll 8
    for (int t = 0; t < 64; t++) s += ew[base + (size_t)t * 1024];
    segsum[(b * 16 + seg) * 1024 + d] = s;
}

// ---------- scan stage 2: exclusive prefix of segment sums + shifts ----------
__global__ __launch_bounds__(64) void k_scan2(const float* __restrict__ ew, float* __restrict__ segsum,
                                              float* __restrict__ sfb, float* __restrict__ sbb) {
    int bx = blockIdx.x;            // grid 64 = 4b x 16dch
    int b = bx >> 4, dch = bx & 15;
    int d = dch * 64 + threadIdx.x;
    float run = 0.f, off8 = 0.f;
#pragma unroll
    for (int s = 0; s < 16; s++) {
        int idx = (b * 16 + s) * 1024 + d;
        float t = segsum[idx];
        segsum[idx] = run;
        if (s == 8) off8 = run;
        run += t;
    }
    float e512 = ew[((size_t)(b * 1024 + 512)) * 1024 + d];
    sbb[b * 1024 + d] = off8;          // cs[511]
    sfb[b * 1024 + d] = off8 + e512;   // cs[512]
}

// ---------- scan stage 3: emit clipped cf/cb ----------
__global__ __launch_bounds__(64) void k_scan3(const float* __restrict__ ew, const float* __restrict__ segsum,
                                              const float* __restrict__ sfb, const float* __restrict__ sbb,
                                              float* __restrict__ cf, float* __restrict__ cb) {
    int bx = blockIdx.x;            // grid 1024
    int b = bx >> 8, seg = (bx >> 4) & 15, dch = bx & 15;
    int d = dch * 64 + threadIdx.x;
    float cum = segsum[(b * 16 + seg) * 1024 + d];
    float sf = sfb[b * 1024 + d], sb = sbb[b * 1024 + d];
    size_t base = ((size_t)(b * 1024 + seg * 64)) * 1024 + d;
#pragma unroll 4
    for (int t = 0; t < 64; t++) {
        float prev = cum;
        cum += ew[base + (size_t)t * 1024];
        cf[base + (size_t)t * 1024] = fminf(fmaxf(cum - sf, -60.f), 60.f);
        cb[base + (size_t)t * 1024] = fminf(fmaxf(prev - sb, -60.f), 60.f);
    }
}

// ---------- bf16 MFMA GEMM core: C[4096][1024] = A @ W^T ----------
// modes: 0 fp32 out, 1 silu fp32, 2 q-exp (O1=qf,O2=qb), 3 k-exp (O1=kf,O2=kb), 4 v-transpose (O1=vvt)
__device__ __forceinline__ void gemm_body(const unsigned short* __restrict__ A,
                                          const unsigned short* __restrict__ W,
                                          int m0, int n0, int mode,
                                          float* __restrict__ Cf,
                                          unsigned short* __restrict__ O1,
                                          unsigned short* __restrict__ O2,
                                          const float* __restrict__ cfp,
                                          const float* __restrict__ cbp,
                                          char* smem) {
    int tid = threadIdx.x;
    int w = tid >> 6, lane = tid & 63, l15 = lane & 15, qd = lane >> 4;
    int wm = w >> 1, wn = w & 1;
    fx4 acc[4][4];
#pragma unroll
    for (int mt = 0; mt < 4; mt++)
#pragma unroll
        for (int nt = 0; nt < 4; nt++)
#pragma unroll
            for (int r = 0; r < 4; r++) acc[mt][nt][r] = 0.f;
    unsigned short* sA = (unsigned short*)smem;            // [128][32]
    unsigned short* sB = (unsigned short*)(smem + 8192);   // [128][32]
    int rowA = tid >> 2, cA = tid & 3;
    for (int kb = 0; kb < 1024; kb += 32) {
        __syncthreads();
        uint4 va0 = *(const uint4*)(A + (size_t)(m0 + rowA) * 1024 + kb + cA * 8);
        uint4 va1 = *(const uint4*)(A + (size_t)(m0 + rowA + 64) * 1024 + kb + cA * 8);
        uint4 vb0 = *(const uint4*)(W + (size_t)(n0 + rowA) * 1024 + kb + cA * 8);
        uint4 vb1 = *(const uint4*)(W + (size_t)(n0 + rowA + 64) * 1024 + kb + cA * 8);
        *(uint4*)(sA + tid * 8)        = va0;
        *(uint4*)(sA + tid * 8 + 2048) = va1;
        *(uint4*)(sB + tid * 8)        = vb0;
        *(uint4*)(sB + tid * 8 + 2048) = vb1;
        __syncthreads();
        bh8 af[4], bfr[4];
#pragma unroll
        for (int mt = 0; mt < 4; mt++)
            af[mt] = *(const bh8*)(sA + (wm * 64 + mt * 16 + l15) * 32 + qd * 8);
#pragma unroll
        for (int nt = 0; nt < 4; nt++)
            bfr[nt] = *(const bh8*)(sB + (wn * 64 + nt * 16 + l15) * 32 + qd * 8);
#pragma unroll
        for (int mt = 0; mt < 4; mt++)
#pragma unroll
            for (int nt = 0; nt < 4; nt++)
                acc[mt][nt] = __builtin_amdgcn_mfma_f32_16x16x32_bf16(af[mt], bfr[nt], acc[mt][nt], 0, 0, 0);
    }
    int mb = m0 + wm * 64, nb = n0 + wn * 64;
    if (mode <= 1) {
#pragma unroll
        for (int mt = 0; mt < 4; mt++)
#pragma unroll
            for (int nt = 0; nt < 4; nt++) {
                fx4 s = acc[mt][nt];
#pragma unroll
                for (int r = 0; r < 4; r++) {
                    float v = s[r];
                    if (mode == 1) v = v / (1.f + __expf(-v));
                    Cf[(size_t)(mb + mt * 16 + qd * 4 + r) * 1024 + nb + nt * 16 + l15] = v;
                }
            }
    } else if (mode <= 3) {
        float s1 = (mode == 2) ? 1.f : -1.f;
#pragma unroll
        for (int mt = 0; mt < 4; mt++)
#pragma unroll
            for (int nt = 0; nt < 4; nt++) {
                fx4 s = acc[mt][nt];
#pragma unroll
                for (int r = 0; r < 4; r++) {
                    size_t idx = (size_t)(mb + mt * 16 + qd * 4 + r) * 1024 + nb + nt * 16 + l15;
                    float v = s[r];
                    O1[idx] = f2bf(v * __expf(s1 * cfp[idx]));
                    O2[idx] = f2bf(v * __expf(-s1 * cbp[idx]));
                }
            }
    } else {
        // transpose epilogue -> vvt[(b*1024 + d)][t]
        __syncthreads();
        unsigned short* T = (unsigned short*)smem;   // [128][136]
#pragma unroll
        for (int mt = 0; mt < 4; mt++)
#pragma unroll
            for (int nt = 0; nt < 4; nt++) {
                fx4 s = acc[mt][nt];
                int dl = wn * 64 + nt * 16 + l15;
                int tl = wm * 64 + mt * 16 + qd * 4;
                uint2 pk;
                pk.x = ((unsigned)f2bf(s[1]) << 16) | f2bf(s[0]);
                pk.y = ((unsigned)f2bf(s[3]) << 16) | f2bf(s[2]);
                *(uint2*)(T + dl * 136 + tl) = pk;
            }
        __syncthreads();
        int dl = tid >> 1, hf = tid & 1;
        int bq = m0 >> 10, t0 = m0 & 1023;
#pragma unroll
        for (int i = 0; i < 8; i++) {
            uint4 vv4 = *(const uint4*)(T + dl * 136 + hf * 64 + i * 8);
            *(uint4*)(O1 + (size_t)(bq * 1024 + n0 + dl) * 1024 + t0 + hf * 64 + i * 8) = vv4;
        }
    }
}

__global__ __launch_bounds__(256, 2) void k_gemm4(const unsigned short* __restrict__ xr16,
                                                  const unsigned short* __restrict__ xk16,
                                                  const unsigned short* __restrict__ xv16,
                                                  const unsigned short* __restrict__ xg16,
                                                  const unsigned short* __restrict__ Wrb,
                                                  const unsigned short* __restrict__ Wkb,
                                                  const unsigned short* __restrict__ Wvb,
                                                  const unsigned short* __restrict__ Wgb,
                                                  unsigned short* __restrict__ qf, unsigned short* __restrict__ qb,
                                                  unsigned short* __restrict__ kf, unsigned short* __restrict__ kb,
                                                  unsigned short* __restrict__ vvt,
                                                  float* __restrict__ gg,
                                                  const float* __restrict__ cf, const float* __restrict__ cb) {
    __shared__ __align__(16) char smem[34816];
    int m0 = (blockIdx.x >> 3) * 128, n0 = (blockIdx.x & 7) * 128;
    int y = blockIdx.y;
    if (y == 0)      gemm_body(xr16, Wrb, m0, n0, 2, nullptr, qf, qb, cf, cb, smem);
    else if (y == 1) gemm_body(xk16, Wkb, m0, n0, 3, nullptr, kf, kb, cf, cb, smem);
    else if (y == 2) gemm_body(xv16, Wvb, m0, n0, 4, nullptr, vvt, nullptr, nullptr, nullptr, smem);
    else             gemm_body(xg16, Wgb, m0, n0, 1, gg, nullptr, nullptr, nullptr, nullptr, smem);
}

__global__ __launch_bounds__(256, 2) void k_gemmo(const unsigned short* __restrict__ z16,
                                                  const unsigned short* __restrict__ Wob,
                                                  float* __restrict__ out) {
    __shared__ __align__(16) char smem[34816];
    gemm_body(z16, Wob, (blockIdx.x >> 3) * 128, (blockIdx.x & 7) * 128, 0, out,
              nullptr, nullptr, nullptr, nullptr, smem);
}

// ---------- attention: bidirectional LION via MFMA, barrier-free j-loop ----------
__global__ __launch_bounds__(256, 2) void k_attn(const unsigned short* __restrict__ qf,
                                                 const unsigned short* __restrict__ qb,
                                                 const unsigned short* __restrict__ kf,
                                                 const unsigned short* __restrict__ kb,
                                                 const unsigned short* __restrict__ vvt,
                                                 float* __restrict__ y) {
    __shared__ unsigned short Ss[128 * 72];
    int tid = threadIdx.x;
    int w = tid >> 6, lane = tid & 63, l15 = lane & 15, qd = lane >> 4;
    int bid = blockIdx.x;            // grid 512 = 64 bh x 8 i-tiles
    int bh = bid >> 3, ib = bid & 7;
    int b = bh >> 4, h = bh & 15;
    int I0 = ib * 128;
    int i0w = I0 + w * 32;
    int bt0 = b * 1024;
    fx4 yacc[2][4];
#pragma unroll
    for (int a = 0; a < 2; a++)
#pragma unroll
        for (int c = 0; c < 4; c++)
#pragma unroll
            for (int r = 0; r < 4; r++) yacc[a][c][r] = 0.f;

    for (int phase = 0; phase < 2; phase++) {
        const unsigned short* Q = phase ? qb : qf;
        const unsigned short* K = phase ? kb : kf;
        bh8 qfr[2][2];
#pragma unroll
        for (int nt2 = 0; nt2 < 2; nt2++)
#pragma unroll
            for (int ks = 0; ks < 2; ks++)
                qfr[nt2][ks] = *(const bh8*)(Q + (size_t)(bt0 + i0w + nt2 * 16 + l15) * 1024
                                               + h * 64 + ks * 32 + qd * 8);
        int jlo = phase == 0 ? 0 : 2 * ib;
        int jhi = phase == 0 ? 2 * ib + 1 : 15;
        for (int jt = jlo; jt <= jhi; jt++) {
            int jb = jt * 64;
            bool skip, needmask;
            if (phase == 0) { skip = (jb > i0w + 31); needmask = (jb + 63 > i0w); }
            else            { skip = (i0w >= jb + 63); needmask = (i0w + 31 >= jb); }
            if (skip) continue;
            // S^T tile: rows j, cols i   (A = k-side, B = q-side)
            fx4 sacc[4][2];
#pragma unroll
            for (int mt = 0; mt < 4; mt++)
#pragma unroll
                for (int nt = 0; nt < 2; nt++)
#pragma unroll
                    for (int r = 0; r < 4; r++) sacc[mt][nt][r] = 0.f;
#pragma unroll
            for (int ks = 0; ks < 2; ks++)
#pragma unroll
                for (int mt = 0; mt < 4; mt++) {
                    bh8 kfr = *(const bh8*)(K + (size_t)(bt0 + jb + mt * 16 + l15) * 1024
                                              + h * 64 + ks * 32 + qd * 8);
#pragma unroll
                    for (int nt = 0; nt < 2; nt++)
                        sacc[mt][nt] = __builtin_amdgcn_mfma_f32_16x16x32_bf16(kfr, qfr[nt][ks], sacc[mt][nt], 0, 0, 0);
                }
            // mask + pack to bf16 strip (wave-private)
#pragma unroll
            for (int mt = 0; mt < 4; mt++)
#pragma unroll
                for (int nt = 0; nt < 2; nt++) {
                    fx4 s = sacc[mt][nt];
                    if (needmask) {
                        int ii = i0w + nt * 16 + l15;
                        int jj0 = jb + mt * 16 + qd * 4;
#pragma unroll
                        for (int r = 0; r < 4; r++) {
                            bool keep = (phase == 0) ? (ii >= jj0 + r) : (ii < jj0 + r);
                            if (!keep) s[r] = 0.f;
                        }
                    }
                    uint2 pk;
                    pk.x = ((unsigned)f2bf(s[1]) << 16) | f2bf(s[0]);
                    pk.y = ((unsigned)f2bf(s[3]) << 16) | f2bf(s[2]);
                    *(uint2*)(&Ss[(w * 32 + nt * 16 + l15) * 72 + mt * 16 + qd * 4]) = pk;
                }
            asm volatile("s_waitcnt lgkmcnt(0)" ::: "memory");
            // y += S @ V    (A = S from LDS, B = V^T from global)
#pragma unroll
            for (int ks2 = 0; ks2 < 2; ks2++) {
                bh8 vfr[4];
#pragma unroll
                for (int nt4 = 0; nt4 < 4; nt4++)
                    vfr[nt4] = *(const bh8*)(vvt + (size_t)(b * 1024 + h * 64 + nt4 * 16 + l15) * 1024
                                                 + jb + ks2 * 32 + qd * 8);
#pragma unroll
                for (int mt2 = 0; mt2 < 2; mt2++) {
                    bh8 sa = *(const bh8*)(&Ss[(w * 32 + mt2 * 16 + l15) * 72 + ks2 * 32 + qd * 8]);
#pragma unroll
                    for (int nt4 = 0; nt4 < 4; nt4++)
                        yacc[mt2][nt4] = __builtin_amdgcn_mfma_f32_16x16x32_bf16(sa, vfr[nt4], yacc[mt2][nt4], 0, 0, 0);
                }
            }
        }
    }
#pragma unroll
    for (int mt2 = 0; mt2 < 2; mt2++)
#pragma unroll
        for (int nt4 = 0; nt4 < 4; nt4++) {
            fx4 s = yacc[mt2][nt4];
#pragma unroll
            for (int r = 0; r < 4; r++)
                y[(size_t)(bt0 + i0w + mt2 * 16 + qd * 4 + r) * 1024 + h * 64 + nt4 * 16 + l15] = s[r];
        }
}

// ---------- groupnorm * g -> bf16 z ----------
__global__ __launch_bounds__(256) void k_gn(const float* __restrict__ y,
                                            const float* __restrict__ g,
                                            const float* __restrict__ lnw,
                                            const float* __restrict__ lnb,
                                            unsigned short* __restrict__ z16) {
    int tid = threadIdx.x;
    int lane = tid & 63;
    int wv = tid >> 6;
    int group = blockIdx.x * 4 + wv;     // grid 16384
    int tok = group >> 4, h = group & 15;
    int d = h * 64 + lane;
    float val = y[tok * 1024 + d];
    float s = val, s2 = val * val;
#pragma unroll
    for (int off = 32; off > 0; off >>= 1) {
        s  += __shfl_xor(s, off, 64);
        s2 += __shfl_xor(s2, off, 64);
    }
    float mu = s * (1.f / 64.f);
    float var = s2 * (1.f / 64.f) - mu * mu;
    float inv = rsqrtf(var + 6.4e-4f);
    float yn = (val - mu) * inv * lnw[d] + lnb[d];
    z16[tok * 1024 + d] = f2bf(yn * g[tok * 1024 + d]);
}

extern "C" void kernel_launch(void* const* d_in, const int* in_sizes, int n_in,
                              void* d_out, int out_size, void* d_ws, size_t ws_size,
                              hipStream_t stream) {
    const float* x     = (const float*)d_in[0];
    const float* maa_x = (const float*)d_in[1];
    const float* maa_w = (const float*)d_in[2];
    const float* maa_k = (const float*)d_in[3];
    const float* maa_v = (const float*)d_in[4];
    const float* maa_r = (const float*)d_in[5];
    const float* maa_g = (const float*)d_in[6];
    const float* w1    = (const float*)d_in[7];
    const float* w2    = (const float*)d_in[8];
    const float* tdec  = (const float*)d_in[9];
    const float* dw1   = (const float*)d_in[10];
    const float* dw2   = (const float*)d_in[11];
    const float* W_r   = (const float*)d_in[12];
    const float* W_k   = (const float*)d_in[13];
    const float* W_v   = (const float*)d_in[14];
    const float* W_g   = (const float*)d_in[15];
    const float* W_o   = (const float*)d_in[16];
    const float* lnw   = (const float*)d_in[17];
    const float* lnb   = (const float*)d_in[18];

    float* ws = (float*)d_ws;
    size_t o = 0;
    float* xmix   = ws + o; o += 4194304;   // also ew after k_xxx
    float* xxx    = ws + o; o += 655360;
    float* xw     = ws + o; o += 4194304;   // also y after k_dec1
    float* dech   = ws + o; o += 262144;
    float* segsum = ws + o; o += 65536;
    float* sfb    = ws + o; o += 4096;
    float* sbb    = ws + o; o += 4096;
    float* cf     = ws + o; o += 4194304;
    float* cb     = ws + o; o += 4194304;
    float* gg     = ws + o; o += 4194304;
    unsigned short* us = (unsigned short*)(ws + o);
    size_t u = 0;
    unsigned short* xr16 = us + u; u += 4194304;   // also z16 after gemm4
    unsigned short* xk16 = us + u; u += 4194304;
    unsigned short* xv16 = us + u; u += 4194304;
    unsigned short* xg16 = us + u; u += 4194304;
    unsigned short* qf   = us + u; u += 4194304;
    unsigned short* qb   = us + u; u += 4194304;
    unsigned short* kf   = us + u; u += 4194304;
    unsigned short* kb   = us + u; u += 4194304;
    unsigned short* vvt  = us + u; u += 4194304;
    unsigned short* Wrb  = us + u; u += 1048576;
    unsigned short* Wkb  = us + u; u += 1048576;
    unsigned short* Wvb  = us + u; u += 1048576;
    unsigned short* Wgb  = us + u; u += 1048576;
    unsigned short* Wob  = us + u; u += 1048576;
    float* ew  = xmix;
    float* yb  = xw;
    unsigned short* z16 = xr16;

    k_wconv<<<dim3(512, 5), 256, 0, stream>>>(W_r, W_k, W_v, W_g, W_o, Wrb, Wkb, Wvb, Wgb, Wob);
    k_mixx<<<16384, 256, 0, stream>>>(x, maa_x, xmix);
    k_xxx<<<256, 256, 0, stream>>>(xmix, w1, xxx);
    k_mix5<<<512, 256, 0, stream>>>(x, xxx, w2, maa_w, maa_k, maa_v, maa_r, maa_g,
                                    xw, xk16, xv16, xr16, xg16);
    k_dec1<<<64, 256, 0, stream>>>(xw, dw1, dech);
    k_dec2<<<512, 256, 0, stream>>>(dech, dw2, tdec, ew);
    k_scan1<<<1024, 64, 0, stream>>>(ew, segsum);
    k_scan2<<<64, 64, 0, stream>>>(ew, segsum, sfb, sbb);
    k_scan3<<<1024, 64, 0, stream>>>(ew, segsum, sfb, sbb, cf, cb);
    k_gemm4<<<dim3(256, 4), 256, 0, stream>>>(xr16, xk16, xv16, xg16, Wrb, Wkb, Wvb, Wgb,
                                              qf, qb, kf, kb, vvt, gg, cf, cb);
    k_attn<<<512, 256, 0, stream>>>(qf, qb, kf, kb, vvt, yb);
    k_gn<<<16384, 256, 0, stream>>>(yb, gg, lnw, lnb, z16);
    k_gemmo<<<256, 256, 0, stream>>>(z16, Wob, (float*)d_out);
}

// Round 3
// 597.037 us; speedup vs baseline: 3.3140x; 1.6660x over previous
//
#include <hip/hip_runtime.h>
#include <math.h>

#define NB 4
#define TT 1024
#define DD 1024
#define NTOK 4096
#define ND (NTOK*DD)

typedef __attribute__((ext_vector_type(8))) short bh8;
typedef __attribute__((ext_vector_type(4))) float fx4;

__device__ __forceinline__ unsigned short f2bf(float f) {
    unsigned int b = __float_as_uint(f);
    b += 0x7fffu + ((b >> 16) & 1u);
    return (unsigned short)(b >> 16);
}

// async global->LDS, 16B per lane, LDS dst = wave-uniform base + lane*16
#define GLD16(gp, lp) __builtin_amdgcn_global_load_lds( \
    (__attribute__((address_space(1))) void*)(gp), \
    (__attribute__((address_space(3))) void*)(lp), 16, 0, 0)

// ---------- weight fp32 -> bf16 (5 DxD mats) ----------
__global__ __launch_bounds__(256) void k_wconv(const float* __restrict__ s0, const float* __restrict__ s1,
                                               const float* __restrict__ s2, const float* __restrict__ s3,
                                               const float* __restrict__ s4,
                                               unsigned short* __restrict__ d0, unsigned short* __restrict__ d1,
                                               unsigned short* __restrict__ d2, unsigned short* __restrict__ d3,
                                               unsigned short* __restrict__ d4) {
    const float* s; unsigned short* d;
    switch (blockIdx.y) {
        case 0: s = s0; d = d0; break;
        case 1: s = s1; d = d1; break;
        case 2: s = s2; d = d2; break;
        case 3: s = s3; d = d3; break;
        default: s = s4; d = d4; break;
    }
    int i = (blockIdx.x * 256 + threadIdx.x) * 8;   // grid (512,5)
    float4 a = *(const float4*)(s + i);
    float4 b = *(const float4*)(s + i + 4);
    uint4 o;
    o.x = ((unsigned)f2bf(a.y) << 16) | f2bf(a.x);
    o.y = ((unsigned)f2bf(a.w) << 16) | f2bf(a.z);
    o.z = ((unsigned)f2bf(b.y) << 16) | f2bf(b.x);
    o.w = ((unsigned)f2bf(b.w) << 16) | f2bf(b.z);
    *(uint4*)(d + i) = o;
}

// ---------- transpose+convert: dst[C][1024] = bf16(src[1024][C]) ----------
__global__ __launch_bounds__(256) void k_tconv(const float* __restrict__ src,
                                               unsigned short* __restrict__ dst, int C) {
    int o = blockIdx.x * 256 + threadIdx.x;     // grid 1024*C/256
    int r = o & 1023, c = o >> 10;
    dst[o] = f2bf(src[r * C + c]);
}

// ---------- k1: xmix16 = bf16(x + dxprev * maa_x) ----------
__global__ __launch_bounds__(256) void k_mixx(const float* __restrict__ x,
                                              const float* __restrict__ maa_x,
                                              unsigned short* __restrict__ xmix16) {
    int base = (blockIdx.x * 256 + threadIdx.x) * 4;   // grid 4096
    int t = (base >> 10) & 1023;
    int d = base & 1023;
    float4 xv = *(const float4*)(x + base);
    float4 xm = (t > 0)    ? *(const float4*)(x + base - 1024) : make_float4(0, 0, 0, 0);
    float4 xp = (t < 1023) ? *(const float4*)(x + base + 1024) : make_float4(0, 0, 0, 0);
    float4 ma = *(const float4*)(maa_x + d);
    uint2 o;
    float a0 = xv.x + (0.5f * (xm.x + xp.x) - xv.x) * ma.x;
    float a1 = xv.y + (0.5f * (xm.y + xp.y) - xv.y) * ma.y;
    float a2 = xv.z + (0.5f * (xm.z + xp.z) - xv.z) * ma.z;
    float a3 = xv.w + (0.5f * (xm.w + xp.w) - xv.w) * ma.w;
    o.x = ((unsigned)f2bf(a1) << 16) | f2bf(a0);
    o.y = ((unsigned)f2bf(a3) << 16) | f2bf(a2);
    *(uint2*)(xmix16 + base) = o;
}

// ---------- k2: xxx = tanh(xmix @ w1)  via MFMA, barrier-free ----------
__global__ __launch_bounds__(256) void k_xxx2(const unsigned short* __restrict__ xmix16,
                                              const unsigned short* __restrict__ w1T,
                                              float* __restrict__ xxx) {
    int tid = threadIdx.x;
    int w = tid >> 6, lane = tid & 63, l15 = lane & 15, qd = lane >> 4;
    int m0 = blockIdx.x * 64 + w * 16;    // grid 64
    fx4 acc[10];
#pragma unroll
    for (int nt = 0; nt < 10; nt++)
#pragma unroll
        for (int r = 0; r < 4; r++) acc[nt][r] = 0.f;
#pragma unroll 2
    for (int kb = 0; kb < 1024; kb += 32) {
        bh8 af = *(const bh8*)(xmix16 + (size_t)(m0 + l15) * 1024 + kb + qd * 8);
#pragma unroll
        for (int nt = 0; nt < 10; nt++) {
            bh8 bf = *(const bh8*)(w1T + (size_t)(nt * 16 + l15) * 1024 + kb + qd * 8);
            acc[nt] = __builtin_amdgcn_mfma_f32_16x16x32_bf16(af, bf, acc[nt], 0, 0, 0);
        }
    }
#pragma unroll
    for (int nt = 0; nt < 10; nt++)
#pragma unroll
        for (int r = 0; r < 4; r++)
            xxx[(size_t)(m0 + qd * 4 + r) * 160 + nt * 16 + l15] = tanhf(acc[nt][r]);
}

// ---------- k3: mm einsum + five mixes (bf16 outs) ----------
__global__ __launch_bounds__(256) void k_mix5(const float* __restrict__ x,
                                              const float* __restrict__ xxx,
                                              const float* __restrict__ w2,
                                              const float* __restrict__ maa_w,
                                              const float* __restrict__ maa_k,
                                              const float* __restrict__ maa_v,
                                              const float* __restrict__ maa_r,
                                              const float* __restrict__ maa_g,
                                              unsigned short* __restrict__ xw16,
                                              unsigned short* __restrict__ xk16,
                                              unsigned short* __restrict__ xv16,
                                              unsigned short* __restrict__ xr16,
                                              unsigned short* __restrict__ xg16) {
    __shared__ float xl[8][160];
    int tid = threadIdx.x;
    int tok0 = blockIdx.x * 8;      // grid 512
#pragma unroll
    for (int i = 0; i < 5; i++) {
        int l = tid + i * 256;
        xl[l / 160][l % 160] = xxx[tok0 * 160 + l];
    }
    __syncthreads();
#pragma unroll 1
    for (int c = 0; c < 4; c++) {
        int d = c * 256 + tid;
        float acc[5][8];
#pragma unroll
        for (int f = 0; f < 5; f++)
#pragma unroll
            for (int g = 0; g < 8; g++) acc[f][g] = 0.f;
#pragma unroll
        for (int f = 0; f < 5; f++) {
#pragma unroll 8
            for (int m = 0; m < 32; m++) {
                float wv = w2[(f * 32 + m) * 1024 + d];
#pragma unroll
                for (int g = 0; g < 8; g++)
                    acc[f][g] = fmaf(xl[g][f * 32 + m], wv, acc[f][g]);
            }
        }
        float maas[5] = {maa_w[d], maa_k[d], maa_v[d], maa_r[d], maa_g[d]};
#pragma unroll
        for (int g = 0; g < 8; g++) {
            int tok = tok0 + g;
            int t = tok & 1023;
            float xin = x[tok * 1024 + d];
            float xm1 = (t > 0)    ? x[(tok - 1) * 1024 + d] : 0.f;
            float xp1 = (t < 1023) ? x[(tok + 1) * 1024 + d] : 0.f;
            float dx = 0.5f * (xm1 + xp1) - xin;
            xw16[tok * 1024 + d] = f2bf(xin + dx * (maas[0] + acc[0][g]));
            xk16[tok * 1024 + d] = f2bf(xin + dx * (maas[1] + acc[1][g]));
            xv16[tok * 1024 + d] = f2bf(xin + dx * (maas[2] + acc[2][g]));
            xr16[tok * 1024 + d] = f2bf(xin + dx * (maas[3] + acc[3][g]));
            xg16[tok * 1024 + d] = f2bf(xin + dx * (maas[4] + acc[4][g]));
        }
    }
}

// ---------- decay GEMM1 via MFMA: dech = tanh(xw @ dw1), f32 out ----------
__global__ __launch_bounds__(256) void k_dec1m(const unsigned short* __restrict__ xw16,
                                               const unsigned short* __restrict__ dw1T,
                                               float* __restrict__ dech) {
    int tid = threadIdx.x;
    int w = tid >> 6, lane = tid & 63, l15 = lane & 15, qd = lane >> 4;
    int m0 = blockIdx.x * 64 + w * 16;    // grid 64
    fx4 acc[4];
#pragma unroll
    for (int nt = 0; nt < 4; nt++)
#pragma unroll
        for (int r = 0; r < 4; r++) acc[nt][r] = 0.f;
#pragma unroll 2
    for (int kb = 0; kb < 1024; kb += 32) {
        bh8 af = *(const bh8*)(xw16 + (size_t)(m0 + l15) * 1024 + kb + qd * 8);
#pragma unroll
        for (int nt = 0; nt < 4; nt++) {
            bh8 bf = *(const bh8*)(dw1T + (size_t)(nt * 16 + l15) * 1024 + kb + qd * 8);
            acc[nt] = __builtin_amdgcn_mfma_f32_16x16x32_bf16(af, bf, acc[nt], 0, 0, 0);
        }
    }
#pragma unroll
    for (int nt = 0; nt < 4; nt++)
#pragma unroll
        for (int r = 0; r < 4; r++)
            dech[(size_t)(m0 + qd * 4 + r) * 64 + nt * 16 + l15] = tanhf(acc[nt][r]);
}

// ---------- decay GEMM2: ew = -exp(time_decay + dech @ dw2) ----------
__global__ __launch_bounds__(256) void k_dec2(const float* __restrict__ dech,
                                              const float* __restrict__ dw2,
                                              const float* __restrict__ tdec,
                                              float* __restrict__ ew) {
    __shared__ float hl[8][64];
    int tid = threadIdx.x;
    int tok0 = blockIdx.x * 8;     // grid 512
    {
        int l = tid;        hl[l >> 6][l & 63] = dech[tok0 * 64 + l];
        l = tid + 256;      hl[l >> 6][l & 63] = dech[tok0 * 64 + l];
    }
    __syncthreads();
#pragma unroll 1
    for (int c = 0; c < 4; c++) {
        int d = c * 256 + tid;
        float acc[8] = {};
#pragma unroll 8
        for (int j = 0; j < 64; j++) {
            float wv = dw2[j * 1024 + d];
#pragma unroll
            for (int g = 0; g < 8; g++) acc[g] = fmaf(hl[g][j], wv, acc[g]);
        }
        float td = tdec[d];
#pragma unroll
        for (int g = 0; g < 8; g++) ew[(tok0 + g) * 1024 + d] = -expf(td + acc[g]);
    }
}

// ---------- scan stage 1: per-segment sums ----------
__global__ __launch_bounds__(64) void k_scan1(const float* __restrict__ ew, float* __restrict__ segsum) {
    int bx = blockIdx.x;            // grid 1024 = 4b x 16seg x 16dch
    int b = bx >> 8, seg = (bx >> 4) & 15, dch = bx & 15;
    int d = dch * 64 + threadIdx.x;
    size_t base = ((size_t)(b * 1024 + seg * 64)) * 1024 + d;
    float s = 0.f;
#pragma unroll 8
    for (int t = 0; t < 64; t++) s += ew[base + (size_t)t * 1024];
    segsum[(b * 16 + seg) * 1024 + d] = s;
}

// ---------- scan stage 2: exclusive prefix of segment sums + shifts ----------
__global__ __launch_bounds__(64) void k_scan2(const float* __restrict__ ew, float* __restrict__ segsum,
                                              float* __restrict__ sfb, float* __restrict__ sbb) {
    int bx = blockIdx.x;            // grid 64 = 4b x 16dch
    int b = bx >> 4, dch = bx & 15;
    int d = dch * 64 + threadIdx.x;
    float run = 0.f, off8 = 0.f;
#pragma unroll
    for (int s = 0; s < 16; s++) {
        int idx = (b * 16 + s) * 1024 + d;
        float t = segsum[idx];
        segsum[idx] = run;
        if (s == 8) off8 = run;
        run += t;
    }
    float e512 = ew[((size_t)(b * 1024 + 512)) * 1024 + d];
    sbb[b * 1024 + d] = off8;          // cs[511]
    sfb[b * 1024 + d] = off8 + e512;   // cs[512]
}

// ---------- scan stage 3: emit clipped cf/cb ----------
__global__ __launch_bounds__(64) void k_scan3(const float* __restrict__ ew, const float* __restrict__ segsum,
                                              const float* __restrict__ sfb, const float* __restrict__ sbb,
                                              float* __restrict__ cf, float* __restrict__ cb) {
    int bx = blockIdx.x;            // grid 1024
    int b = bx >> 8, seg = (bx >> 4) & 15, dch = bx & 15;
    int d = dch * 64 + threadIdx.x;
    float cum = segsum[(b * 16 + seg) * 1024 + d];
    float sf = sfb[b * 1024 + d], sb = sbb[b * 1024 + d];
    size_t base = ((size_t)(b * 1024 + seg * 64)) * 1024 + d;
#pragma unroll 4
    for (int t = 0; t < 64; t++) {
        float prev = cum;
        cum += ew[base + (size_t)t * 1024];
        cf[base + (size_t)t * 1024] = fminf(fmaxf(cum - sf, -60.f), 60.f);
        cb[base + (size_t)t * 1024] = fminf(fmaxf(prev - sb, -60.f), 60.f);
    }
}

// ---------- bf16 MFMA GEMM core: C[4096][1024] = A @ W^T, async LDS staging ----------
// modes: 0 fp32 out, 1 silu fp32, 2 q-exp (O1=qf,O2=qb), 3 k-exp (O1=kf,O2=kb), 4 v-transpose (O1=vvt)
__device__ __forceinline__ void gemm_body(const unsigned short* __restrict__ A,
                                          const unsigned short* __restrict__ W,
                                          int m0, int n0, int mode,
                                          float* __restrict__ Cf,
                                          unsigned short* __restrict__ O1,
                                          unsigned short* __restrict__ O2,
                                          const float* __restrict__ cfp,
                                          const float* __restrict__ cbp,
                                          char* smem) {
    int tid = threadIdx.x;
    int w = tid >> 6, lane = tid & 63, l15 = lane & 15, qd = lane >> 4;
    int wm = w >> 1, wn = w & 1;
    fx4 acc[4][4];
#pragma unroll
    for (int mt = 0; mt < 4; mt++)
#pragma unroll
        for (int nt = 0; nt < 4; nt++)
#pragma unroll
            for (int r = 0; r < 4; r++) acc[mt][nt][r] = 0.f;
    unsigned short* sA = (unsigned short*)smem;            // [128][32]
    unsigned short* sB = (unsigned short*)(smem + 8192);   // [128][32]
    int rowA = tid >> 2, cA = tid & 3;
    for (int kb = 0; kb < 1024; kb += 32) {
        __syncthreads();
        GLD16(A + (size_t)(m0 + rowA) * 1024 + kb + cA * 8,      sA + w * 512);
        GLD16(A + (size_t)(m0 + 64 + rowA) * 1024 + kb + cA * 8, sA + 2048 + w * 512);
        GLD16(W + (size_t)(n0 + rowA) * 1024 + kb + cA * 8,      sB + w * 512);
        GLD16(W + (size_t)(n0 + 64 + rowA) * 1024 + kb + cA * 8, sB + 2048 + w * 512);
        __syncthreads();
        bh8 af[4], bfr[4];
#pragma unroll
        for (int mt = 0; mt < 4; mt++)
            af[mt] = *(const bh8*)(sA + (wm * 64 + mt * 16 + l15) * 32 + qd * 8);
#pragma unroll
        for (int nt = 0; nt < 4; nt++)
            bfr[nt] = *(const bh8*)(sB + (wn * 64 + nt * 16 + l15) * 32 + qd * 8);
#pragma unroll
        for (int mt = 0; mt < 4; mt++)
#pragma unroll
            for (int nt = 0; nt < 4; nt++)
                acc[mt][nt] = __builtin_amdgcn_mfma_f32_16x16x32_bf16(af[mt], bfr[nt], acc[mt][nt], 0, 0, 0);
    }
    int mb = m0 + wm * 64, nb = n0 + wn * 64;
    if (mode <= 1) {
#pragma unroll
        for (int mt = 0; mt < 4; mt++)
#pragma unroll
            for (int nt = 0; nt < 4; nt++) {
                fx4 s = acc[mt][nt];
#pragma unroll
                for (int r = 0; r < 4; r++) {
                    float v = s[r];
                    if (mode == 1) v = v / (1.f + __expf(-v));
                    Cf[(size_t)(mb + mt * 16 + qd * 4 + r) * 1024 + nb + nt * 16 + l15] = v;
                }
            }
    } else if (mode <= 3) {
        float s1 = (mode == 2) ? 1.f : -1.f;
#pragma unroll
        for (int mt = 0; mt < 4; mt++)
#pragma unroll
            for (int nt = 0; nt < 4; nt++) {
                fx4 s = acc[mt][nt];
#pragma unroll
                for (int r = 0; r < 4; r++) {
                    size_t idx = (size_t)(mb + mt * 16 + qd * 4 + r) * 1024 + nb + nt * 16 + l15;
                    float v = s[r];
                    O1[idx] = f2bf(v * __expf(s1 * cfp[idx]));
                    O2[idx] = f2bf(v * __expf(-s1 * cbp[idx]));
                }
            }
    } else {
        // transpose epilogue -> vvt[(b*1024 + d)][t]
        __syncthreads();
        unsigned short* T = (unsigned short*)smem;   // [128][136]
#pragma unroll
        for (int mt = 0; mt < 4; mt++)
#pragma unroll
            for (int nt = 0; nt < 4; nt++) {
                fx4 s = acc[mt][nt];
                int dl = wn * 64 + nt * 16 + l15;
                int tl = wm * 64 + mt * 16 + qd * 4;
                uint2 pk;
                pk.x = ((unsigned)f2bf(s[1]) << 16) | f2bf(s[0]);
                pk.y = ((unsigned)f2bf(s[3]) << 16) | f2bf(s[2]);
                *(uint2*)(T + dl * 136 + tl) = pk;
            }
        __syncthreads();
        int dl = tid >> 1, hf = tid & 1;
        int bq = m0 >> 10, t0 = m0 & 1023;
#pragma unroll
        for (int i = 0; i < 8; i++) {
            uint4 vv4 = *(const uint4*)(T + dl * 136 + hf * 64 + i * 8);
            *(uint4*)(O1 + (size_t)(bq * 1024 + n0 + dl) * 1024 + t0 + hf * 64 + i * 8) = vv4;
        }
    }
}

__global__ __launch_bounds__(256, 2) void k_gemm4(const unsigned short* __restrict__ xr16,
                                                  const unsigned short* __restrict__ xk16,
                                                  const unsigned short* __restrict__ xv16,
                                                  const unsigned short* __restrict__ xg16,
                                                  const unsigned short* __restrict__ Wrb,
                                                  const unsigned short* __restrict__ Wkb,
                                                  const unsigned short* __restrict__ Wvb,
                                                  const unsigned short* __restrict__ Wgb,
                                                  unsigned short* __restrict__ qf, unsigned short* __restrict__ qb,
                                                  unsigned short* __restrict__ kf, unsigned short* __restrict__ kb,
                                                  unsigned short* __restrict__ vvt,
                                                  float* __restrict__ gg,
                                                  const float* __restrict__ cf, const float* __restrict__ cb) {
    __shared__ __align__(16) char smem[34816];
    int m0 = (blockIdx.x >> 3) * 128, n0 = (blockIdx.x & 7) * 128;
    int y = blockIdx.y;
    if (y == 0)      gemm_body(xr16, Wrb, m0, n0, 2, nullptr, qf, qb, cf, cb, smem);
    else if (y == 1) gemm_body(xk16, Wkb, m0, n0, 3, nullptr, kf, kb, cf, cb, smem);
    else if (y == 2) gemm_body(xv16, Wvb, m0, n0, 4, nullptr, vvt, nullptr, nullptr, nullptr, smem);
    else             gemm_body(xg16, Wgb, m0, n0, 1, gg, nullptr, nullptr, nullptr, nullptr, smem);
}

__global__ __launch_bounds__(256, 2) void k_gemmo(const unsigned short* __restrict__ z16,
                                                  const unsigned short* __restrict__ Wob,
                                                  float* __restrict__ out) {
    __shared__ __align__(16) char smem[34816];
    gemm_body(z16, Wob, (blockIdx.x >> 3) * 128, (blockIdx.x & 7) * 128, 0, out,
              nullptr, nullptr, nullptr, nullptr, smem);
}

// ---------- attention: bidirectional LION via MFMA, barrier-free j-loop ----------
__global__ __launch_bounds__(256, 2) void k_attn(const unsigned short* __restrict__ qf,
                                                 const unsigned short* __restrict__ qb,
                                                 const unsigned short* __restrict__ kf,
                                                 const unsigned short* __restrict__ kb,
                                                 const unsigned short* __restrict__ vvt,
                                                 float* __restrict__ y) {
    __shared__ unsigned short Ss[128 * 72];
    int tid = threadIdx.x;
    int w = tid >> 6, lane = tid & 63, l15 = lane & 15, qd = lane >> 4;
    int bid = blockIdx.x;            // grid 512 = 64 bh x 8 i-tiles
    int bh = bid >> 3, ib = bid & 7;
    int b = bh >> 4, h = bh & 15;
    int I0 = ib * 128;
    int i0w = I0 + w * 32;
    int bt0 = b * 1024;
    fx4 yacc[2][4];
#pragma unroll
    for (int a = 0; a < 2; a++)
#pragma unroll
        for (int c = 0; c < 4; c++)
#pragma unroll
            for (int r = 0; r < 4; r++) yacc[a][c][r] = 0.f;

    for (int phase = 0; phase < 2; phase++) {
        const unsigned short* Q = phase ? qb : qf;
        const unsigned short* K = phase ? kb : kf;
        bh8 qfr[2][2];
#pragma unroll
        for (int nt2 = 0; nt2 < 2; nt2++)
#pragma unroll
            for (int ks = 0; ks < 2; ks++)
                qfr[nt2][ks] = *(const bh8*)(Q + (size_t)(bt0 + i0w + nt2 * 16 + l15) * 1024
                                               + h * 64 + ks * 32 + qd * 8);
        int jlo = phase == 0 ? 0 : 2 * ib;
        int jhi = phase == 0 ? 2 * ib + 1 : 15;
        for (int jt = jlo; jt <= jhi; jt++) {
            int jb = jt * 64;
            bool skip, needmask;
            if (phase == 0) { skip = (jb > i0w + 31); needmask = (jb + 63 > i0w); }
            else            { skip = (i0w >= jb + 63); needmask = (i0w + 31 >= jb); }
            if (skip) continue;
            // S^T tile: rows j, cols i   (A = k-side, B = q-side)
            fx4 sacc[4][2];
#pragma unroll
            for (int mt = 0; mt < 4; mt++)
#pragma unroll
                for (int nt = 0; nt < 2; nt++)
#pragma unroll
                    for (int r = 0; r < 4; r++) sacc[mt][nt][r] = 0.f;
#pragma unroll
            for (int ks = 0; ks < 2; ks++)
#pragma unroll
                for (int mt = 0; mt < 4; mt++) {
                    bh8 kfr = *(const bh8*)(K + (size_t)(bt0 + jb + mt * 16 + l15) * 1024
                                              + h * 64 + ks * 32 + qd * 8);
#pragma unroll
                    for (int nt = 0; nt < 2; nt++)
                        sacc[mt][nt] = __builtin_amdgcn_mfma_f32_16x16x32_bf16(kfr, qfr[nt][ks], sacc[mt][nt], 0, 0, 0);
                }
            // mask + pack to bf16 strip (wave-private)
#pragma unroll
            for (int mt = 0; mt < 4; mt++)
#pragma unroll
                for (int nt = 0; nt < 2; nt++) {
                    fx4 s = sacc[mt][nt];
                    if (needmask) {
                        int ii = i0w + nt * 16 + l15;
                        int jj0 = jb + mt * 16 + qd * 4;
#pragma unroll
                        for (int r = 0; r < 4; r++) {
                            bool keep = (phase == 0) ? (ii >= jj0 + r) : (ii < jj0 + r);
                            if (!keep) s[r] = 0.f;
                        }
                    }
                    uint2 pk;
                    pk.x = ((unsigned)f2bf(s[1]) << 16) | f2bf(s[0]);
                    pk.y = ((unsigned)f2bf(s[3]) << 16) | f2bf(s[2]);
                    *(uint2*)(&Ss[(w * 32 + nt * 16 + l15) * 72 + mt * 16 + qd * 4]) = pk;
                }
            asm volatile("s_waitcnt lgkmcnt(0)" ::: "memory");
            // y += S @ V    (A = S from LDS, B = V^T from global)
#pragma unroll
            for (int ks2 = 0; ks2 < 2; ks2++) {
                bh8 vfr[4];
#pragma unroll
                for (int nt4 = 0; nt4 < 4; nt4++)
                    vfr[nt4] = *(const bh8*)(vvt + (size_t)(b * 1024 + h * 64 + nt4 * 16 + l15) * 1024
                                                 + jb + ks2 * 32 + qd * 8);
#pragma unroll
                for (int mt2 = 0; mt2 < 2; mt2++) {
                    bh8 sa = *(const bh8*)(&Ss[(w * 32 + mt2 * 16 + l15) * 72 + ks2 * 32 + qd * 8]);
#pragma unroll
                    for (int nt4 = 0; nt4 < 4; nt4++)
                        yacc[mt2][nt4] = __builtin_amdgcn_mfma_f32_16x16x32_bf16(sa, vfr[nt4], yacc[mt2][nt4], 0, 0, 0);
                }
            }
        }
    }
#pragma unroll
    for (int mt2 = 0; mt2 < 2; mt2++)
#pragma unroll
        for (int nt4 = 0; nt4 < 4; nt4++) {
            fx4 s = yacc[mt2][nt4];
#pragma unroll
            for (int r = 0; r < 4; r++)
                y[(size_t)(bt0 + i0w + mt2 * 16 + qd * 4 + r) * 1024 + h * 64 + nt4 * 16 + l15] = s[r];
        }
}

// ---------- groupnorm * g -> bf16 z ----------
__global__ __launch_bounds__(256) void k_gn(const float* __restrict__ y,
                                            const float* __restrict__ g,
                                            const float* __restrict__ lnw,
                                            const float* __restrict__ lnb,
                                            unsigned short* __restrict__ z16) {
    int tid = threadIdx.x;
    int lane = tid & 63;
    int wv = tid >> 6;
    int group = blockIdx.x * 4 + wv;     // grid 16384
    int tok = group >> 4, h = group & 15;
    int d = h * 64 + lane;
    float val = y[tok * 1024 + d];
    float s = val, s2 = val * val;
#pragma unroll
    for (int off = 32; off > 0; off >>= 1) {
        s  += __shfl_xor(s, off, 64);
        s2 += __shfl_xor(s2, off, 64);
    }
    float mu = s * (1.f / 64.f);
    float var = s2 * (1.f / 64.f) - mu * mu;
    float inv = rsqrtf(var + 6.4e-4f);
    float yn = (val - mu) * inv * lnw[d] + lnb[d];
    z16[tok * 1024 + d] = f2bf(yn * g[tok * 1024 + d]);
}

extern "C" void kernel_launch(void* const* d_in, const int* in_sizes, int n_in,
                              void* d_out, int out_size, void* d_ws, size_t ws_size,
                              hipStream_t stream) {
    const float* x     = (const float*)d_in[0];
    const float* maa_x = (const float*)d_in[1];
    const float* maa_w = (const float*)d_in[2];
    const float* maa_k = (const float*)d_in[3];
    const float* maa_v = (const float*)d_in[4];
    const float* maa_r = (const float*)d_in[5];
    const float* maa_g = (const float*)d_in[6];
    const float* w1    = (const float*)d_in[7];
    const float* w2    = (const float*)d_in[8];
    const float* tdec  = (const float*)d_in[9];
    const float* dw1   = (const float*)d_in[10];
    const float* dw2   = (const float*)d_in[11];
    const float* W_r   = (const float*)d_in[12];
    const float* W_k   = (const float*)d_in[13];
    const float* W_v   = (const float*)d_in[14];
    const float* W_g   = (const float*)d_in[15];
    const float* W_o   = (const float*)d_in[16];
    const float* lnw   = (const float*)d_in[17];
    const float* lnb   = (const float*)d_in[18];

    float* ws = (float*)d_ws;
    size_t o = 0;
    float* xxx    = ws + o; o += 655360;
    float* dech   = ws + o; o += 262144;
    float* segsum = ws + o; o += 65536;
    float* sfb    = ws + o; o += 4096;
    float* sbb    = ws + o; o += 4096;
    float* ew     = ws + o; o += 4194304;
    float* cf     = ws + o; o += 4194304;
    float* cb     = ws + o; o += 4194304;
    float* gg     = ws + o; o += 4194304;
    unsigned short* us = (unsigned short*)(ws + o);
    size_t u = 0;
    unsigned short* xmix16 = us + u; u += 4194304;
    unsigned short* xw16 = us + u; u += 4194304;
    unsigned short* xr16 = us + u; u += 4194304;   // also z16 after gemm4
    unsigned short* xk16 = us + u; u += 4194304;
    unsigned short* xv16 = us + u; u += 4194304;
    unsigned short* xg16 = us + u; u += 4194304;
    unsigned short* qf   = us + u; u += 4194304;
    unsigned short* qb   = us + u; u += 4194304;
    unsigned short* kf   = us + u; u += 4194304;
    unsigned short* kb   = us + u; u += 4194304;
    unsigned short* vvt  = us + u; u += 4194304;
    unsigned short* Wrb  = us + u; u += 1048576;
    unsigned short* Wkb  = us + u; u += 1048576;
    unsigned short* Wvb  = us + u; u += 1048576;
    unsigned short* Wgb  = us + u; u += 1048576;
    unsigned short* Wob  = us + u; u += 1048576;
    unsigned short* w1T  = us + u; u += 163840;
    unsigned short* dw1T = us + u; u += 65536;
    float* yb = cf;              // attention out reuses cf (dead after gemm4)
    unsigned short* z16 = xr16;  // dead after gemm4

    k_wconv<<<dim3(512, 5), 256, 0, stream>>>(W_r, W_k, W_v, W_g, W_o, Wrb, Wkb, Wvb, Wgb, Wob);
    k_tconv<<<640, 256, 0, stream>>>(w1, w1T, 160);
    k_tconv<<<256, 256, 0, stream>>>(dw1, dw1T, 64);
    k_mixx<<<4096, 256, 0, stream>>>(x, maa_x, xmix16);
    k_xxx2<<<64, 256, 0, stream>>>(xmix16, w1T, xxx);
    k_mix5<<<512, 256, 0, stream>>>(x, xxx, w2, maa_w, maa_k, maa_v, maa_r, maa_g,
                                    xw16, xk16, xv16, xr16, xg16);
    k_dec1m<<<64, 256, 0, stream>>>(xw16, dw1T, dech);
    k_dec2<<<512, 256, 0, stream>>>(dech, dw2, tdec, ew);
    k_scan1<<<1024, 64, 0, stream>>>(ew, segsum);
    k_scan2<<<64, 64, 0, stream>>>(ew, segsum, sfb, sbb);
    k_scan3<<<1024, 64, 0, stream>>>(ew, segsum, sfb, sbb, cf, cb);
    k_gemm4<<<dim3(256, 4), 256, 0, stream>>>(xr16, xk16, xv16, xg16, Wrb, Wkb, Wvb, Wgb,
                                              qf, qb, kf, kb, vvt, gg, cf, cb);
    k_attn<<<512, 256, 0, stream>>>(qf, qb, kf, kb, vvt, yb);
    k_gn<<<16384, 256, 0, stream>>>(yb, gg, lnw, lnb, z16);
    k_gemmo<<<256, 256, 0, stream>>>(z16, Wob, (float*)d_out);
}

// Round 4
// 425.393 us; speedup vs baseline: 4.6511x; 1.4035x over previous
//
#include <hip/hip_runtime.h>
#include <math.h>

#define NB 4
#define TT 1024
#define DD 1024
#define NTOK 4096
#define ND (NTOK*DD)

typedef __attribute__((ext_vector_type(8))) short bh8;
typedef __attribute__((ext_vector_type(4))) float fx4;

__device__ __forceinline__ unsigned short f2bf(float f) {
    unsigned int b = __float_as_uint(f);
    b += 0x7fffu + ((b >> 16) & 1u);
    return (unsigned short)(b >> 16);
}

// async global->LDS, 16B per lane, LDS dst = wave-uniform base + lane*16
#define GLD16(gp, lp) __builtin_amdgcn_global_load_lds( \
    (__attribute__((address_space(1))) void*)(gp), \
    (__attribute__((address_space(3))) void*)(lp), 16, 0, 0)

// ---------- weight fp32 -> bf16 (5 DxD mats) ----------
__global__ __launch_bounds__(256) void k_wconv(const float* __restrict__ s0, const float* __restrict__ s1,
                                               const float* __restrict__ s2, const float* __restrict__ s3,
                                               const float* __restrict__ s4,
                                               unsigned short* __restrict__ d0, unsigned short* __restrict__ d1,
                                               unsigned short* __restrict__ d2, unsigned short* __restrict__ d3,
                                               unsigned short* __restrict__ d4) {
    const float* s; unsigned short* d;
    switch (blockIdx.y) {
        case 0: s = s0; d = d0; break;
        case 1: s = s1; d = d1; break;
        case 2: s = s2; d = d2; break;
        case 3: s = s3; d = d3; break;
        default: s = s4; d = d4; break;
    }
    int i = (blockIdx.x * 256 + threadIdx.x) * 8;   // grid (512,5)
    float4 a = *(const float4*)(s + i);
    float4 b = *(const float4*)(s + i + 4);
    uint4 o;
    o.x = ((unsigned)f2bf(a.y) << 16) | f2bf(a.x);
    o.y = ((unsigned)f2bf(a.w) << 16) | f2bf(a.z);
    o.z = ((unsigned)f2bf(b.y) << 16) | f2bf(b.x);
    o.w = ((unsigned)f2bf(b.w) << 16) | f2bf(b.z);
    *(uint4*)(d + i) = o;
}

// ---------- transpose+convert: dst[C][1024] = bf16(src[1024][C]) ----------
__global__ __launch_bounds__(256) void k_tconv(const float* __restrict__ src,
                                               unsigned short* __restrict__ dst, int C) {
    int o = blockIdx.x * 256 + threadIdx.x;     // grid 1024*C/256
    int r = o & 1023, c = o >> 10;
    dst[o] = f2bf(src[r * C + c]);
}

// ---------- w2[5][32][1024] -> w2T16[5][1024][32] bf16 ----------
__global__ __launch_bounds__(256) void k_w2t(const float* __restrict__ w2,
                                             unsigned short* __restrict__ w2T16) {
    int d = blockIdx.x * 256 + threadIdx.x;   // grid (4,5)
    int f = blockIdx.y;
#pragma unroll 8
    for (int m = 0; m < 32; m++)
        w2T16[(size_t)(f * 1024 + d) * 32 + m] = f2bf(w2[(size_t)(f * 32 + m) * 1024 + d]);
}

// ---------- k1: xmix16 = bf16(x + dxprev * maa_x) ----------
__global__ __launch_bounds__(256) void k_mixx(const float* __restrict__ x,
                                              const float* __restrict__ maa_x,
                                              unsigned short* __restrict__ xmix16) {
    int base = (blockIdx.x * 256 + threadIdx.x) * 4;   // grid 4096
    int t = (base >> 10) & 1023;
    int d = base & 1023;
    float4 xv = *(const float4*)(x + base);
    float4 xm = (t > 0)    ? *(const float4*)(x + base - 1024) : make_float4(0, 0, 0, 0);
    float4 xp = (t < 1023) ? *(const float4*)(x + base + 1024) : make_float4(0, 0, 0, 0);
    float4 ma = *(const float4*)(maa_x + d);
    uint2 o;
    float a0 = xv.x + (0.5f * (xm.x + xp.x) - xv.x) * ma.x;
    float a1 = xv.y + (0.5f * (xm.y + xp.y) - xv.y) * ma.y;
    float a2 = xv.z + (0.5f * (xm.z + xp.z) - xv.z) * ma.z;
    float a3 = xv.w + (0.5f * (xm.w + xp.w) - xv.w) * ma.w;
    o.x = ((unsigned)f2bf(a1) << 16) | f2bf(a0);
    o.y = ((unsigned)f2bf(a3) << 16) | f2bf(a2);
    *(uint2*)(xmix16 + base) = o;
}

// ---------- k2: xxx16 = bf16(tanh(xmix @ w1)) via MFMA, barrier-free ----------
__global__ __launch_bounds__(256) void k_xxx2(const unsigned short* __restrict__ xmix16,
                                              const unsigned short* __restrict__ w1T,
                                              unsigned short* __restrict__ xxx16) {
    int tid = threadIdx.x;
    int w = tid >> 6, lane = tid & 63, l15 = lane & 15, qd = lane >> 4;
    int m0 = blockIdx.x * 64 + w * 16;    // grid 64
    fx4 acc[10];
#pragma unroll
    for (int nt = 0; nt < 10; nt++)
#pragma unroll
        for (int r = 0; r < 4; r++) acc[nt][r] = 0.f;
#pragma unroll 2
    for (int kb = 0; kb < 1024; kb += 32) {
        bh8 af = *(const bh8*)(xmix16 + (size_t)(m0 + l15) * 1024 + kb + qd * 8);
#pragma unroll
        for (int nt = 0; nt < 10; nt++) {
            bh8 bf = *(const bh8*)(w1T + (size_t)(nt * 16 + l15) * 1024 + kb + qd * 8);
            acc[nt] = __builtin_amdgcn_mfma_f32_16x16x32_bf16(af, bf, acc[nt], 0, 0, 0);
        }
    }
#pragma unroll
    for (int nt = 0; nt < 10; nt++)
#pragma unroll
        for (int r = 0; r < 4; r++)
            xxx16[(size_t)(m0 + qd * 4 + r) * 160 + nt * 16 + l15] = f2bf(tanhf(acc[nt][r]));
}

// ---------- k3: fused mm-einsum (MFMA, K=32) + five mixes, no LDS ----------
__global__ __launch_bounds__(256, 2) void k_mmix(const float* __restrict__ x,
                                                 const unsigned short* __restrict__ xxx16,
                                                 const unsigned short* __restrict__ w2T16,
                                                 const float* __restrict__ maa_w,
                                                 const float* __restrict__ maa_k,
                                                 const float* __restrict__ maa_v,
                                                 const float* __restrict__ maa_r,
                                                 const float* __restrict__ maa_g,
                                                 unsigned short* __restrict__ xw16,
                                                 unsigned short* __restrict__ xk16,
                                                 unsigned short* __restrict__ xv16,
                                                 unsigned short* __restrict__ xr16,
                                                 unsigned short* __restrict__ xg16) {
    int tid = threadIdx.x;
    int w = tid >> 6, lane = tid & 63, l15 = lane & 15, qd = lane >> 4;
    int n0 = blockIdx.x * 64;               // grid (16, 32)
    int m0w = blockIdx.y * 128 + w * 32;
    const float* maap[5] = {maa_w, maa_k, maa_v, maa_r, maa_g};
    unsigned short* outp[5] = {xw16, xk16, xv16, xr16, xg16};
    // precompute xin/dx for this wave's 32 C-cells per lane
    float xin[8][4], dxv[8][4];
#pragma unroll
    for (int mi = 0; mi < 2; mi++)
#pragma unroll
        for (int r = 0; r < 4; r++) {
            int tok = m0w + mi * 16 + qd * 4 + r;
            int t = tok & 1023;
#pragma unroll
            for (int ni = 0; ni < 4; ni++) {
                int d = n0 + ni * 16 + l15;
                size_t idx = (size_t)tok * 1024 + d;
                float xv = x[idx];
                float xm1 = (t > 0)    ? x[idx - 1024] : 0.f;
                float xp1 = (t < 1023) ? x[idx + 1024] : 0.f;
                xin[mi * 4 + r][ni] = xv;
                dxv[mi * 4 + r][ni] = 0.5f * (xm1 + xp1) - xv;
            }
        }
#pragma unroll
    for (int f = 0; f < 5; f++) {
        bh8 af[2], bf[4];
#pragma unroll
        for (int mi = 0; mi < 2; mi++)
            af[mi] = *(const bh8*)(xxx16 + (size_t)(m0w + mi * 16 + l15) * 160 + f * 32 + qd * 8);
#pragma unroll
        for (int ni = 0; ni < 4; ni++)
            bf[ni] = *(const bh8*)(w2T16 + (size_t)(f * 1024 + n0 + ni * 16 + l15) * 32 + qd * 8);
        fx4 acc[2][4];
#pragma unroll
        for (int mi = 0; mi < 2; mi++)
#pragma unroll
            for (int ni = 0; ni < 4; ni++) {
#pragma unroll
                for (int r = 0; r < 4; r++) acc[mi][ni][r] = 0.f;
                acc[mi][ni] = __builtin_amdgcn_mfma_f32_16x16x32_bf16(af[mi], bf[ni], acc[mi][ni], 0, 0, 0);
            }
        const float* maa = maap[f];
        unsigned short* op = outp[f];
#pragma unroll
        for (int ni = 0; ni < 4; ni++) {
            float mv = maa[n0 + ni * 16 + l15];
#pragma unroll
            for (int mi = 0; mi < 2; mi++)
#pragma unroll
                for (int r = 0; r < 4; r++) {
                    float o = xin[mi * 4 + r][ni] + dxv[mi * 4 + r][ni] * (mv + acc[mi][ni][r]);
                    op[(size_t)(m0w + mi * 16 + qd * 4 + r) * 1024 + n0 + ni * 16 + l15] = f2bf(o);
                }
        }
    }
}

// ---------- decay GEMM1 via MFMA: dech = tanh(xw @ dw1), f32 out ----------
__global__ __launch_bounds__(256) void k_dec1m(const unsigned short* __restrict__ xw16,
                                               const unsigned short* __restrict__ dw1T,
                                               float* __restrict__ dech) {
    int tid = threadIdx.x;
    int w = tid >> 6, lane = tid & 63, l15 = lane & 15, qd = lane >> 4;
    int m0 = blockIdx.x * 64 + w * 16;    // grid 64
    fx4 acc[4];
#pragma unroll
    for (int nt = 0; nt < 4; nt++)
#pragma unroll
        for (int r = 0; r < 4; r++) acc[nt][r] = 0.f;
#pragma unroll 2
    for (int kb = 0; kb < 1024; kb += 32) {
        bh8 af = *(const bh8*)(xw16 + (size_t)(m0 + l15) * 1024 + kb + qd * 8);
#pragma unroll
        for (int nt = 0; nt < 4; nt++) {
            bh8 bf = *(const bh8*)(dw1T + (size_t)(nt * 16 + l15) * 1024 + kb + qd * 8);
            acc[nt] = __builtin_amdgcn_mfma_f32_16x16x32_bf16(af, bf, acc[nt], 0, 0, 0);
        }
    }
#pragma unroll
    for (int nt = 0; nt < 4; nt++)
#pragma unroll
        for (int r = 0; r < 4; r++)
            dech[(size_t)(m0 + qd * 4 + r) * 64 + nt * 16 + l15] = tanhf(acc[nt][r]);
}

// ---------- decay GEMM2: ew = -exp(time_decay + dech @ dw2) ----------
__global__ __launch_bounds__(256) void k_dec2(const float* __restrict__ dech,
                                              const float* __restrict__ dw2,
                                              const float* __restrict__ tdec,
                                              float* __restrict__ ew) {
    __shared__ float hl[8][64];
    int tid = threadIdx.x;
    int tok0 = blockIdx.x * 8;     // grid 512
    {
        int l = tid;        hl[l >> 6][l & 63] = dech[tok0 * 64 + l];
        l = tid + 256;      hl[l >> 6][l & 63] = dech[tok0 * 64 + l];
    }
    __syncthreads();
#pragma unroll 1
    for (int c = 0; c < 4; c++) {
        int d = c * 256 + tid;
        float acc[8] = {};
#pragma unroll 8
        for (int j = 0; j < 64; j++) {
            float wv = dw2[j * 1024 + d];
#pragma unroll
            for (int g = 0; g < 8; g++) acc[g] = fmaf(hl[g][j], wv, acc[g]);
        }
        float td = tdec[d];
#pragma unroll
        for (int g = 0; g < 8; g++) ew[(tok0 + g) * 1024 + d] = -expf(td + acc[g]);
    }
}

// ---------- scan stage 1: per-segment sums ----------
__global__ __launch_bounds__(64) void k_scan1(const float* __restrict__ ew, float* __restrict__ segsum) {
    int bx = blockIdx.x;            // grid 1024 = 4b x 16seg x 16dch
    int b = bx >> 8, seg = (bx >> 4) & 15, dch = bx & 15;
    int d = dch * 64 + threadIdx.x;
    size_t base = ((size_t)(b * 1024 + seg * 64)) * 1024 + d;
    float s = 0.f;
#pragma unroll 8
    for (int t = 0; t < 64; t++) s += ew[base + (size_t)t * 1024];
    segsum[(b * 16 + seg) * 1024 + d] = s;
}

// ---------- scan stage 2: exclusive prefix of segment sums + shifts ----------
__global__ __launch_bounds__(64) void k_scan2(const float* __restrict__ ew, float* __restrict__ segsum,
                                              float* __restrict__ sfb, float* __restrict__ sbb) {
    int bx = blockIdx.x;            // grid 64 = 4b x 16dch
    int b = bx >> 4, dch = bx & 15;
    int d = dch * 64 + threadIdx.x;
    float run = 0.f, off8 = 0.f;
#pragma unroll
    for (int s = 0; s < 16; s++) {
        int idx = (b * 16 + s) * 1024 + d;
        float t = segsum[idx];
        segsum[idx] = run;
        if (s == 8) off8 = run;
        run += t;
    }
    float e512 = ew[((size_t)(b * 1024 + 512)) * 1024 + d];
    sbb[b * 1024 + d] = off8;          // cs[511]
    sfb[b * 1024 + d] = off8 + e512;   // cs[512]
}

// ---------- scan stage 3: emit clipped cf/cb ----------
__global__ __launch_bounds__(64) void k_scan3(const float* __restrict__ ew, const float* __restrict__ segsum,
                                              const float* __restrict__ sfb, const float* __restrict__ sbb,
                                              float* __restrict__ cf, float* __restrict__ cb) {
    int bx = blockIdx.x;            // grid 1024
    int b = bx >> 8, seg = (bx >> 4) & 15, dch = bx & 15;
    int d = dch * 64 + threadIdx.x;
    float cum = segsum[(b * 16 + seg) * 1024 + d];
    float sf = sfb[b * 1024 + d], sb = sbb[b * 1024 + d];
    size_t base = ((size_t)(b * 1024 + seg * 64)) * 1024 + d;
#pragma unroll 4
    for (int t = 0; t < 64; t++) {
        float prev = cum;
        cum += ew[base + (size_t)t * 1024];
        cf[base + (size_t)t * 1024] = fminf(fmaxf(cum - sf, -60.f), 60.f);
        cb[base + (size_t)t * 1024] = fminf(fmaxf(prev - sb, -60.f), 60.f);
    }
}

// ---------- bf16 MFMA GEMM core: C[4096][1024] = A @ W^T, async LDS staging ----------
// modes: 0 fp32 out, 1 silu fp32, 2 q-exp (O1=qf,O2=qb), 3 k-exp (O1=kf,O2=kb), 4 v-transpose (O1=vvt)
__device__ __forceinline__ void gemm_body(const unsigned short* __restrict__ A,
                                          const unsigned short* __restrict__ W,
                                          int m0, int n0, int mode,
                                          float* __restrict__ Cf,
                                          unsigned short* __restrict__ O1,
                                          unsigned short* __restrict__ O2,
                                          const float* __restrict__ cfp,
                                          const float* __restrict__ cbp,
                                          char* smem) {
    int tid = threadIdx.x;
    int w = tid >> 6, lane = tid & 63, l15 = lane & 15, qd = lane >> 4;
    int wm = w >> 1, wn = w & 1;
    fx4 acc[4][4];
#pragma unroll
    for (int mt = 0; mt < 4; mt++)
#pragma unroll
        for (int nt = 0; nt < 4; nt++)
#pragma unroll
            for (int r = 0; r < 4; r++) acc[mt][nt][r] = 0.f;
    unsigned short* sA = (unsigned short*)smem;            // [128][32]
    unsigned short* sB = (unsigned short*)(smem + 8192);   // [128][32]
    int rowA = tid >> 2, cA = tid & 3;
    for (int kb = 0; kb < 1024; kb += 32) {
        __syncthreads();
        GLD16(A + (size_t)(m0 + rowA) * 1024 + kb + cA * 8,      sA + w * 512);
        GLD16(A + (size_t)(m0 + 64 + rowA) * 1024 + kb + cA * 8, sA + 2048 + w * 512);
        GLD16(W + (size_t)(n0 + rowA) * 1024 + kb + cA * 8,      sB + w * 512);
        GLD16(W + (size_t)(n0 + 64 + rowA) * 1024 + kb + cA * 8, sB + 2048 + w * 512);
        __syncthreads();
        bh8 af[4], bfr[4];
#pragma unroll
        for (int mt = 0; mt < 4; mt++)
            af[mt] = *(const bh8*)(sA + (wm * 64 + mt * 16 + l15) * 32 + qd * 8);
#pragma unroll
        for (int nt = 0; nt < 4; nt++)
            bfr[nt] = *(const bh8*)(sB + (wn * 64 + nt * 16 + l15) * 32 + qd * 8);
#pragma unroll
        for (int mt = 0; mt < 4; mt++)
#pragma unroll
            for (int nt = 0; nt < 4; nt++)
                acc[mt][nt] = __builtin_amdgcn_mfma_f32_16x16x32_bf16(af[mt], bfr[nt], acc[mt][nt], 0, 0, 0);
    }
    int mb = m0 + wm * 64, nb = n0 + wn * 64;
    if (mode <= 1) {
#pragma unroll
        for (int mt = 0; mt < 4; mt++)
#pragma unroll
            for (int nt = 0; nt < 4; nt++) {
                fx4 s = acc[mt][nt];
#pragma unroll
                for (int r = 0; r < 4; r++) {
                    float v = s[r];
                    if (mode == 1) v = v / (1.f + __expf(-v));
                    Cf[(size_t)(mb + mt * 16 + qd * 4 + r) * 1024 + nb + nt * 16 + l15] = v;
                }
            }
    } else if (mode <= 3) {
        float s1 = (mode == 2) ? 1.f : -1.f;
#pragma unroll
        for (int mt = 0; mt < 4; mt++)
#pragma unroll
            for (int nt = 0; nt < 4; nt++) {
                fx4 s = acc[mt][nt];
#pragma unroll
                for (int r = 0; r < 4; r++) {
                    size_t idx = (size_t)(mb + mt * 16 + qd * 4 + r) * 1024 + nb + nt * 16 + l15;
                    float v = s[r];
                    O1[idx] = f2bf(v * __expf(s1 * cfp[idx]));
                    O2[idx] = f2bf(v * __expf(-s1 * cbp[idx]));
                }
            }
    } else {
        // transpose epilogue -> vvt[(b*1024 + d)][t]
        __syncthreads();
        unsigned short* T = (unsigned short*)smem;   // [128][136]
#pragma unroll
        for (int mt = 0; mt < 4; mt++)
#pragma unroll
            for (int nt = 0; nt < 4; nt++) {
                fx4 s = acc[mt][nt];
                int dl = wn * 64 + nt * 16 + l15;
                int tl = wm * 64 + mt * 16 + qd * 4;
                uint2 pk;
                pk.x = ((unsigned)f2bf(s[1]) << 16) | f2bf(s[0]);
                pk.y = ((unsigned)f2bf(s[3]) << 16) | f2bf(s[2]);
                *(uint2*)(T + dl * 136 + tl) = pk;
            }
        __syncthreads();
        int dl = tid >> 1, hf = tid & 1;
        int bq = m0 >> 10, t0 = m0 & 1023;
#pragma unroll
        for (int i = 0; i < 8; i++) {
            uint4 vv4 = *(const uint4*)(T + dl * 136 + hf * 64 + i * 8);
            *(uint4*)(O1 + (size_t)(bq * 1024 + n0 + dl) * 1024 + t0 + hf * 64 + i * 8) = vv4;
        }
    }
}

__global__ __launch_bounds__(256, 2) void k_gemm4(const unsigned short* __restrict__ xr16,
                                                  const unsigned short* __restrict__ xk16,
                                                  const unsigned short* __restrict__ xv16,
                                                  const unsigned short* __restrict__ xg16,
                                                  const unsigned short* __restrict__ Wrb,
                                                  const unsigned short* __restrict__ Wkb,
                                                  const unsigned short* __restrict__ Wvb,
                                                  const unsigned short* __restrict__ Wgb,
                                                  unsigned short* __restrict__ qf, unsigned short* __restrict__ qb,
                                                  unsigned short* __restrict__ kf, unsigned short* __restrict__ kb,
                                                  unsigned short* __restrict__ vvt,
                                                  float* __restrict__ gg,
                                                  const float* __restrict__ cf, const float* __restrict__ cb) {
    __shared__ __align__(16) char smem[34816];
    int m0 = (blockIdx.x >> 3) * 128, n0 = (blockIdx.x & 7) * 128;
    int y = blockIdx.y;
    if (y == 0)      gemm_body(xr16, Wrb, m0, n0, 2, nullptr, qf, qb, cf, cb, smem);
    else if (y == 1) gemm_body(xk16, Wkb, m0, n0, 3, nullptr, kf, kb, cf, cb, smem);
    else if (y == 2) gemm_body(xv16, Wvb, m0, n0, 4, nullptr, vvt, nullptr, nullptr, nullptr, smem);
    else             gemm_body(xg16, Wgb, m0, n0, 1, gg, nullptr, nullptr, nullptr, nullptr, smem);
}

__global__ __launch_bounds__(256, 2) void k_gemmo(const unsigned short* __restrict__ z16,
                                                  const unsigned short* __restrict__ Wob,
                                                  float* __restrict__ out) {
    __shared__ __align__(16) char smem[34816];
    gemm_body(z16, Wob, (blockIdx.x >> 3) * 128, (blockIdx.x & 7) * 128, 0, out,
              nullptr, nullptr, nullptr, nullptr, smem);
}

// ---------- attention: bidirectional LION via MFMA, barrier-free j-loop ----------
__global__ __launch_bounds__(256, 2) void k_attn(const unsigned short* __restrict__ qf,
                                                 const unsigned short* __restrict__ qb,
                                                 const unsigned short* __restrict__ kf,
                                                 const unsigned short* __restrict__ kb,
                                                 const unsigned short* __restrict__ vvt,
                                                 float* __restrict__ y) {
    __shared__ unsigned short Ss[128 * 72];
    int tid = threadIdx.x;
    int w = tid >> 6, lane = tid & 63, l15 = lane & 15, qd = lane >> 4;
    int bid = blockIdx.x;            // grid 512 = 64 bh x 8 i-tiles
    int bh = bid >> 3, ib = bid & 7;
    int b = bh >> 4, h = bh & 15;
    int I0 = ib * 128;
    int i0w = I0 + w * 32;
    int bt0 = b * 1024;
    fx4 yacc[2][4];
#pragma unroll
    for (int a = 0; a < 2; a++)
#pragma unroll
        for (int c = 0; c < 4; c++)
#pragma unroll
            for (int r = 0; r < 4; r++) yacc[a][c][r] = 0.f;

    for (int phase = 0; phase < 2; phase++) {
        const unsigned short* Q = phase ? qb : qf;
        const unsigned short* K = phase ? kb : kf;
        bh8 qfr[2][2];
#pragma unroll
        for (int nt2 = 0; nt2 < 2; nt2++)
#pragma unroll
            for (int ks = 0; ks < 2; ks++)
                qfr[nt2][ks] = *(const bh8*)(Q + (size_t)(bt0 + i0w + nt2 * 16 + l15) * 1024
                                               + h * 64 + ks * 32 + qd * 8);
        int jlo = phase == 0 ? 0 : 2 * ib;
        int jhi = phase == 0 ? 2 * ib + 1 : 15;
        for (int jt = jlo; jt <= jhi; jt++) {
            int jb = jt * 64;
            bool skip, needmask;
            if (phase == 0) { skip = (jb > i0w + 31); needmask = (jb + 63 > i0w); }
            else            { skip = (i0w >= jb + 63); needmask = (i0w + 31 >= jb); }
            if (skip) continue;
            // S^T tile: rows j, cols i   (A = k-side, B = q-side)
            fx4 sacc[4][2];
#pragma unroll
            for (int mt = 0; mt < 4; mt++)
#pragma unroll
                for (int nt = 0; nt < 2; nt++)
#pragma unroll
                    for (int r = 0; r < 4; r++) sacc[mt][nt][r] = 0.f;
#pragma unroll
            for (int ks = 0; ks < 2; ks++)
#pragma unroll
                for (int mt = 0; mt < 4; mt++) {
                    bh8 kfr = *(const bh8*)(K + (size_t)(bt0 + jb + mt * 16 + l15) * 1024
                                              + h * 64 + ks * 32 + qd * 8);
#pragma unroll
                    for (int nt = 0; nt < 2; nt++)
                        sacc[mt][nt] = __builtin_amdgcn_mfma_f32_16x16x32_bf16(kfr, qfr[nt][ks], sacc[mt][nt], 0, 0, 0);
                }
            // mask + pack to bf16 strip (wave-private)
#pragma unroll
            for (int mt = 0; mt < 4; mt++)
#pragma unroll
                for (int nt = 0; nt < 2; nt++) {
                    fx4 s = sacc[mt][nt];
                    if (needmask) {
                        int ii = i0w + nt * 16 + l15;
                        int jj0 = jb + mt * 16 + qd * 4;
#pragma unroll
                        for (int r = 0; r < 4; r++) {
                            bool keep = (phase == 0) ? (ii >= jj0 + r) : (ii < jj0 + r);
                            if (!keep) s[r] = 0.f;
                        }
                    }
                    uint2 pk;
                    pk.x = ((unsigned)f2bf(s[1]) << 16) | f2bf(s[0]);
                    pk.y = ((unsigned)f2bf(s[3]) << 16) | f2bf(s[2]);
                    *(uint2*)(&Ss[(w * 32 + nt * 16 + l15) * 72 + mt * 16 + qd * 4]) = pk;
                }
            asm volatile("s_waitcnt lgkmcnt(0)" ::: "memory");
            // y += S @ V    (A = S from LDS, B = V^T from global)
#pragma unroll
            for (int ks2 = 0; ks2 < 2; ks2++) {
                bh8 vfr[4];
#pragma unroll
                for (int nt4 = 0; nt4 < 4; nt4++)
                    vfr[nt4] = *(const bh8*)(vvt + (size_t)(b * 1024 + h * 64 + nt4 * 16 + l15) * 1024
                                                 + jb + ks2 * 32 + qd * 8);
#pragma unroll
                for (int mt2 = 0; mt2 < 2; mt2++) {
                    bh8 sa = *(const bh8*)(&Ss[(w * 32 + mt2 * 16 + l15) * 72 + ks2 * 32 + qd * 8]);
#pragma unroll
                    for (int nt4 = 0; nt4 < 4; nt4++)
                        yacc[mt2][nt4] = __builtin_amdgcn_mfma_f32_16x16x32_bf16(sa, vfr[nt4], yacc[mt2][nt4], 0, 0, 0);
                }
            }
        }
    }
#pragma unroll
    for (int mt2 = 0; mt2 < 2; mt2++)
#pragma unroll
        for (int nt4 = 0; nt4 < 4; nt4++) {
            fx4 s = yacc[mt2][nt4];
#pragma unroll
            for (int r = 0; r < 4; r++)
                y[(size_t)(bt0 + i0w + mt2 * 16 + qd * 4 + r) * 1024 + h * 64 + nt4 * 16 + l15] = s[r];
        }
}

// ---------- groupnorm * g -> bf16 z ----------
__global__ __launch_bounds__(256) void k_gn(const float* __restrict__ y,
                                            const float* __restrict__ g,
                                            const float* __restrict__ lnw,
                                            const float* __restrict__ lnb,
                                            unsigned short* __restrict__ z16) {
    int tid = threadIdx.x;
    int lane = tid & 63;
    int wv = tid >> 6;
    int group = blockIdx.x * 4 + wv;     // grid 16384
    int tok = group >> 4, h = group & 15;
    int d = h * 64 + lane;
    float val = y[tok * 1024 + d];
    float s = val, s2 = val * val;
#pragma unroll
    for (int off = 32; off > 0; off >>= 1) {
        s  += __shfl_xor(s, off, 64);
        s2 += __shfl_xor(s2, off, 64);
    }
    float mu = s * (1.f / 64.f);
    float var = s2 * (1.f / 64.f) - mu * mu;
    float inv = rsqrtf(var + 6.4e-4f);
    float yn = (val - mu) * inv * lnw[d] + lnb[d];
    z16[tok * 1024 + d] = f2bf(yn * g[tok * 1024 + d]);
}

extern "C" void kernel_launch(void* const* d_in, const int* in_sizes, int n_in,
                              void* d_out, int out_size, void* d_ws, size_t ws_size,
                              hipStream_t stream) {
    const float* x     = (const float*)d_in[0];
    const float* maa_x = (const float*)d_in[1];
    const float* maa_w = (const float*)d_in[2];
    const float* maa_k = (const float*)d_in[3];
    const float* maa_v = (const float*)d_in[4];
    const float* maa_r = (const float*)d_in[5];
    const float* maa_g = (const float*)d_in[6];
    const float* w1    = (const float*)d_in[7];
    const float* w2    = (const float*)d_in[8];
    const float* tdec  = (const float*)d_in[9];
    const float* dw1   = (const float*)d_in[10];
    const float* dw2   = (const float*)d_in[11];
    const float* W_r   = (const float*)d_in[12];
    const float* W_k   = (const float*)d_in[13];
    const float* W_v   = (const float*)d_in[14];
    const float* W_g   = (const float*)d_in[15];
    const float* W_o   = (const float*)d_in[16];
    const float* lnw   = (const float*)d_in[17];
    const float* lnb   = (const float*)d_in[18];

    float* ws = (float*)d_ws;
    size_t o = 0;
    float* dech   = ws + o; o += 262144;
    float* segsum = ws + o; o += 65536;
    float* sfb    = ws + o; o += 4096;
    float* sbb    = ws + o; o += 4096;
    float* ew     = ws + o; o += 4194304;
    float* cf     = ws + o; o += 4194304;
    float* cb     = ws + o; o += 4194304;
    float* gg     = ws + o; o += 4194304;
    unsigned short* us = (unsigned short*)(ws + o);
    size_t u = 0;
    unsigned short* xmix16 = us + u; u += 4194304;
    unsigned short* xw16 = us + u; u += 4194304;
    unsigned short* xr16 = us + u; u += 4194304;   // also z16 after gemm4
    unsigned short* xk16 = us + u; u += 4194304;
    unsigned short* xv16 = us + u; u += 4194304;
    unsigned short* xg16 = us + u; u += 4194304;
    unsigned short* qf   = us + u; u += 4194304;
    unsigned short* qb   = us + u; u += 4194304;
    unsigned short* kf   = us + u; u += 4194304;
    unsigned short* kb   = us + u; u += 4194304;
    unsigned short* vvt  = us + u; u += 4194304;
    unsigned short* Wrb  = us + u; u += 1048576;
    unsigned short* Wkb  = us + u; u += 1048576;
    unsigned short* Wvb  = us + u; u += 1048576;
    unsigned short* Wgb  = us + u; u += 1048576;
    unsigned short* Wob  = us + u; u += 1048576;
    unsigned short* w1T  = us + u; u += 163840;
    unsigned short* dw1T = us + u; u += 65536;
    unsigned short* xxx16 = us + u; u += 655360;
    unsigned short* w2T16 = us + u; u += 163840;
    float* yb = cf;              // attention out reuses cf (dead after gemm4)
    unsigned short* z16 = xr16;  // dead after gemm4

    k_wconv<<<dim3(512, 5), 256, 0, stream>>>(W_r, W_k, W_v, W_g, W_o, Wrb, Wkb, Wvb, Wgb, Wob);
    k_tconv<<<640, 256, 0, stream>>>(w1, w1T, 160);
    k_tconv<<<256, 256, 0, stream>>>(dw1, dw1T, 64);
    k_w2t<<<dim3(4, 5), 256, 0, stream>>>(w2, w2T16);
    k_mixx<<<4096, 256, 0, stream>>>(x, maa_x, xmix16);
    k_xxx2<<<64, 256, 0, stream>>>(xmix16, w1T, xxx16);
    k_mmix<<<dim3(16, 32), 256, 0, stream>>>(x, xxx16, w2T16, maa_w, maa_k, maa_v, maa_r, maa_g,
                                             xw16, xk16, xv16, xr16, xg16);
    k_dec1m<<<64, 256, 0, stream>>>(xw16, dw1T, dech);
    k_dec2<<<512, 256, 0, stream>>>(dech, dw2, tdec, ew);
    k_scan1<<<1024, 64, 0, stream>>>(ew, segsum);
    k_scan2<<<64, 64, 0, stream>>>(ew, segsum, sfb, sbb);
    k_scan3<<<1024, 64, 0, stream>>>(ew, segsum, sfb, sbb, cf, cb);
    k_gemm4<<<dim3(256, 4), 256, 0, stream>>>(xr16, xk16, xv16, xg16, Wrb, Wkb, Wvb, Wgb,
                                              qf, qb, kf, kb, vvt, gg, cf, cb);
    k_attn<<<512, 256, 0, stream>>>(qf, qb, kf, kb, vvt, yb);
    k_gn<<<16384, 256, 0, stream>>>(yb, gg, lnw, lnb, z16);
    k_gemmo<<<256, 256, 0, stream>>>(z16, Wob, (float*)d_out);
}

// Round 5
// 395.304 us; speedup vs baseline: 5.0052x; 1.0761x over previous
//
#include <hip/hip_runtime.h>
#include <math.h>

#define NB 4
#define TT 1024
#define DD 1024
#define NTOK 4096
#define ND (NTOK*DD)

typedef __attribute__((ext_vector_type(8))) short bh8;
typedef __attribute__((ext_vector_type(4))) float fx4;

__device__ __forceinline__ unsigned short f2bf(float f) {
    unsigned int b = __float_as_uint(f);
    b += 0x7fffu + ((b >> 16) & 1u);
    return (unsigned short)(b >> 16);
}

// async global->LDS, 16B per lane, LDS dst = wave-uniform base + lane*16
#define GLD16(gp, lp) __builtin_amdgcn_global_load_lds( \
    (__attribute__((address_space(1))) void*)(gp), \
    (__attribute__((address_space(3))) void*)(lp), 16, 0, 0)

// ---------- weight fp32 -> bf16 (5 DxD mats) ----------
__global__ __launch_bounds__(256) void k_wconv(const float* __restrict__ s0, const float* __restrict__ s1,
                                               const float* __restrict__ s2, const float* __restrict__ s3,
                                               const float* __restrict__ s4,
                                               unsigned short* __restrict__ d0, unsigned short* __restrict__ d1,
                                               unsigned short* __restrict__ d2, unsigned short* __restrict__ d3,
                                               unsigned short* __restrict__ d4) {
    const float* s; unsigned short* d;
    switch (blockIdx.y) {
        case 0: s = s0; d = d0; break;
        case 1: s = s1; d = d1; break;
        case 2: s = s2; d = d2; break;
        case 3: s = s3; d = d3; break;
        default: s = s4; d = d4; break;
    }
    int i = (blockIdx.x * 256 + threadIdx.x) * 8;   // grid (512,5)
    float4 a = *(const float4*)(s + i);
    float4 b = *(const float4*)(s + i + 4);
    uint4 o;
    o.x = ((unsigned)f2bf(a.y) << 16) | f2bf(a.x);
    o.y = ((unsigned)f2bf(a.w) << 16) | f2bf(a.z);
    o.z = ((unsigned)f2bf(b.y) << 16) | f2bf(b.x);
    o.w = ((unsigned)f2bf(b.w) << 16) | f2bf(b.z);
    *(uint4*)(d + i) = o;
}

// ---------- transpose+convert: dst[C][1024] = bf16(src[1024][C]) ----------
__global__ __launch_bounds__(256) void k_tconv(const float* __restrict__ src,
                                               unsigned short* __restrict__ dst, int C) {
    int o = blockIdx.x * 256 + threadIdx.x;     // grid 1024*C/256
    int r = o & 1023, c = o >> 10;
    dst[o] = f2bf(src[r * C + c]);
}

// ---------- w2[5][32][1024] -> w2T16[5][1024][32] bf16 ----------
__global__ __launch_bounds__(256) void k_w2t(const float* __restrict__ w2,
                                             unsigned short* __restrict__ w2T16) {
    int d = blockIdx.x * 256 + threadIdx.x;   // grid (4,5)
    int f = blockIdx.y;
#pragma unroll 8
    for (int m = 0; m < 32; m++)
        w2T16[(size_t)(f * 1024 + d) * 32 + m] = f2bf(w2[(size_t)(f * 32 + m) * 1024 + d]);
}

// ---------- k1: xmix16 = bf16(x + dxprev * maa_x) ----------
__global__ __launch_bounds__(256) void k_mixx(const float* __restrict__ x,
                                              const float* __restrict__ maa_x,
                                              unsigned short* __restrict__ xmix16) {
    int base = (blockIdx.x * 256 + threadIdx.x) * 4;   // grid 4096
    int t = (base >> 10) & 1023;
    int d = base & 1023;
    float4 xv = *(const float4*)(x + base);
    float4 xm = (t > 0)    ? *(const float4*)(x + base - 1024) : make_float4(0, 0, 0, 0);
    float4 xp = (t < 1023) ? *(const float4*)(x + base + 1024) : make_float4(0, 0, 0, 0);
    float4 ma = *(const float4*)(maa_x + d);
    uint2 o;
    float a0 = xv.x + (0.5f * (xm.x + xp.x) - xv.x) * ma.x;
    float a1 = xv.y + (0.5f * (xm.y + xp.y) - xv.y) * ma.y;
    float a2 = xv.z + (0.5f * (xm.z + xp.z) - xv.z) * ma.z;
    float a3 = xv.w + (0.5f * (xm.w + xp.w) - xv.w) * ma.w;
    o.x = ((unsigned)f2bf(a1) << 16) | f2bf(a0);
    o.y = ((unsigned)f2bf(a3) << 16) | f2bf(a2);
    *(uint2*)(xmix16 + base) = o;
}

// ---------- k2: xxx16 = bf16(tanh(xmix @ w1)) via MFMA, 1-wave blocks ----------
__global__ __launch_bounds__(64) void k_xxx2(const unsigned short* __restrict__ xmix16,
                                             const unsigned short* __restrict__ w1T,
                                             unsigned short* __restrict__ xxx16) {
    int lane = threadIdx.x;
    int l15 = lane & 15, qd = lane >> 4;
    int m0 = blockIdx.x * 16;    // grid 256
    fx4 acc[10];
#pragma unroll
    for (int nt = 0; nt < 10; nt++)
#pragma unroll
        for (int r = 0; r < 4; r++) acc[nt][r] = 0.f;
#pragma unroll 2
    for (int kb = 0; kb < 1024; kb += 32) {
        bh8 af = *(const bh8*)(xmix16 + (size_t)(m0 + l15) * 1024 + kb + qd * 8);
#pragma unroll
        for (int nt = 0; nt < 10; nt++) {
            bh8 bf = *(const bh8*)(w1T + (size_t)(nt * 16 + l15) * 1024 + kb + qd * 8);
            acc[nt] = __builtin_amdgcn_mfma_f32_16x16x32_bf16(af, bf, acc[nt], 0, 0, 0);
        }
    }
#pragma unroll
    for (int nt = 0; nt < 10; nt++)
#pragma unroll
        for (int r = 0; r < 4; r++)
            xxx16[(size_t)(m0 + qd * 4 + r) * 160 + nt * 16 + l15] = f2bf(tanhf(acc[nt][r]));
}

// ---------- k3: fused mm-einsum (MFMA, K=32) + five mixes, no LDS ----------
__global__ __launch_bounds__(256, 2) void k_mmix(const float* __restrict__ x,
                                                 const unsigned short* __restrict__ xxx16,
                                                 const unsigned short* __restrict__ w2T16,
                                                 const float* __restrict__ maa_w,
                                                 const float* __restrict__ maa_k,
                                                 const float* __restrict__ maa_v,
                                                 const float* __restrict__ maa_r,
                                                 const float* __restrict__ maa_g,
                                                 unsigned short* __restrict__ xw16,
                                                 unsigned short* __restrict__ xk16,
                                                 unsigned short* __restrict__ xv16,
                                                 unsigned short* __restrict__ xr16,
                                                 unsigned short* __restrict__ xg16) {
    int tid = threadIdx.x;
    int w = tid >> 6, lane = tid & 63, l15 = lane & 15, qd = lane >> 4;
    int n0 = blockIdx.x * 64;               // grid (16, 32)
    int m0w = blockIdx.y * 128 + w * 32;
    const float* maap[5] = {maa_w, maa_k, maa_v, maa_r, maa_g};
    unsigned short* outp[5] = {xw16, xk16, xv16, xr16, xg16};
    float xin[8][4], dxv[8][4];
#pragma unroll
    for (int mi = 0; mi < 2; mi++)
#pragma unroll
        for (int r = 0; r < 4; r++) {
            int tok = m0w + mi * 16 + qd * 4 + r;
            int t = tok & 1023;
#pragma unroll
            for (int ni = 0; ni < 4; ni++) {
                int d = n0 + ni * 16 + l15;
                size_t idx = (size_t)tok * 1024 + d;
                float xv = x[idx];
                float xm1 = (t > 0)    ? x[idx - 1024] : 0.f;
                float xp1 = (t < 1023) ? x[idx + 1024] : 0.f;
                xin[mi * 4 + r][ni] = xv;
                dxv[mi * 4 + r][ni] = 0.5f * (xm1 + xp1) - xv;
            }
        }
#pragma unroll
    for (int f = 0; f < 5; f++) {
        bh8 af[2], bf[4];
#pragma unroll
        for (int mi = 0; mi < 2; mi++)
            af[mi] = *(const bh8*)(xxx16 + (size_t)(m0w + mi * 16 + l15) * 160 + f * 32 + qd * 8);
#pragma unroll
        for (int ni = 0; ni < 4; ni++)
            bf[ni] = *(const bh8*)(w2T16 + (size_t)(f * 1024 + n0 + ni * 16 + l15) * 32 + qd * 8);
        fx4 acc[2][4];
#pragma unroll
        for (int mi = 0; mi < 2; mi++)
#pragma unroll
            for (int ni = 0; ni < 4; ni++) {
#pragma unroll
                for (int r = 0; r < 4; r++) acc[mi][ni][r] = 0.f;
                acc[mi][ni] = __builtin_amdgcn_mfma_f32_16x16x32_bf16(af[mi], bf[ni], acc[mi][ni], 0, 0, 0);
            }
        const float* maa = maap[f];
        unsigned short* op = outp[f];
#pragma unroll
        for (int ni = 0; ni < 4; ni++) {
            float mv = maa[n0 + ni * 16 + l15];
#pragma unroll
            for (int mi = 0; mi < 2; mi++)
#pragma unroll
                for (int r = 0; r < 4; r++) {
                    float o = xin[mi * 4 + r][ni] + dxv[mi * 4 + r][ni] * (mv + acc[mi][ni][r]);
                    op[(size_t)(m0w + mi * 16 + qd * 4 + r) * 1024 + n0 + ni * 16 + l15] = f2bf(o);
                }
        }
    }
}

// ---------- decay GEMM1 via MFMA: dech = tanh(xw @ dw1), 1-wave blocks ----------
__global__ __launch_bounds__(64) void k_dec1m(const unsigned short* __restrict__ xw16,
                                              const unsigned short* __restrict__ dw1T,
                                              float* __restrict__ dech) {
    int lane = threadIdx.x;
    int l15 = lane & 15, qd = lane >> 4;
    int m0 = blockIdx.x * 16;    // grid 256
    fx4 acc[4];
#pragma unroll
    for (int nt = 0; nt < 4; nt++)
#pragma unroll
        for (int r = 0; r < 4; r++) acc[nt][r] = 0.f;
#pragma unroll 2
    for (int kb = 0; kb < 1024; kb += 32) {
        bh8 af = *(const bh8*)(xw16 + (size_t)(m0 + l15) * 1024 + kb + qd * 8);
#pragma unroll
        for (int nt = 0; nt < 4; nt++) {
            bh8 bf = *(const bh8*)(dw1T + (size_t)(nt * 16 + l15) * 1024 + kb + qd * 8);
            acc[nt] = __builtin_amdgcn_mfma_f32_16x16x32_bf16(af, bf, acc[nt], 0, 0, 0);
        }
    }
#pragma unroll
    for (int nt = 0; nt < 4; nt++)
#pragma unroll
        for (int r = 0; r < 4; r++)
            dech[(size_t)(m0 + qd * 4 + r) * 64 + nt * 16 + l15] = tanhf(acc[nt][r]);
}

// ---------- decay GEMM2: ew = -exp(time_decay + dech @ dw2) ----------
__global__ __launch_bounds__(256) void k_dec2(const float* __restrict__ dech,
                                              const float* __restrict__ dw2,
                                              const float* __restrict__ tdec,
                                              float* __restrict__ ew) {
    __shared__ float hl[8][64];
    int tid = threadIdx.x;
    int tok0 = blockIdx.x * 8;     // grid 512
    {
        int l = tid;        hl[l >> 6][l & 63] = dech[tok0 * 64 + l];
        l = tid + 256;      hl[l >> 6][l & 63] = dech[tok0 * 64 + l];
    }
    __syncthreads();
#pragma unroll 1
    for (int c = 0; c < 4; c++) {
        int d = c * 256 + tid;
        float acc[8] = {};
#pragma unroll 8
        for (int j = 0; j < 64; j++) {
            float wv = dw2[j * 1024 + d];
#pragma unroll
            for (int g = 0; g < 8; g++) acc[g] = fmaf(hl[g][j], wv, acc[g]);
        }
        float td = tdec[d];
#pragma unroll
        for (int g = 0; g < 8; g++) ew[(tok0 + g) * 1024 + d] = -expf(td + acc[g]);
    }
}

// ---------- scan stage 1: per-segment sums (seg = 32) ----------
__global__ __launch_bounds__(64) void k_scan1(const float* __restrict__ ew, float* __restrict__ segsum) {
    int bx = blockIdx.x;            // grid 2048 = 4b x 32seg x 16dch
    int b = bx >> 9, seg = (bx >> 4) & 31, dch = bx & 15;
    int d = dch * 64 + threadIdx.x;
    size_t base = ((size_t)(b * 1024 + seg * 32)) * 1024 + d;
    float s = 0.f;
#pragma unroll 8
    for (int t = 0; t < 32; t++) s += ew[base + (size_t)t * 1024];
    segsum[(b * 32 + seg) * 1024 + d] = s;
}

// ---------- scan stage 2: exclusive prefix of segment sums + shifts ----------
__global__ __launch_bounds__(64) void k_scan2(const float* __restrict__ ew, float* __restrict__ segsum,
                                              float* __restrict__ sfb, float* __restrict__ sbb) {
    int bx = blockIdx.x;            // grid 64 = 4b x 16dch
    int b = bx >> 4, dch = bx & 15;
    int d = dch * 64 + threadIdx.x;
    float run = 0.f, off16 = 0.f;
#pragma unroll
    for (int s = 0; s < 32; s++) {
        int idx = (b * 32 + s) * 1024 + d;
        float t = segsum[idx];
        segsum[idx] = run;
        if (s == 16) off16 = run;
        run += t;
    }
    float e512 = ew[((size_t)(b * 1024 + 512)) * 1024 + d];
    sbb[b * 1024 + d] = off16;          // cs[511]
    sfb[b * 1024 + d] = off16 + e512;   // cs[512]
}

// ---------- scan stage 3: emit clipped cf/cb ----------
__global__ __launch_bounds__(64) void k_scan3(const float* __restrict__ ew, const float* __restrict__ segsum,
                                              const float* __restrict__ sfb, const float* __restrict__ sbb,
                                              float* __restrict__ cf, float* __restrict__ cb) {
    int bx = blockIdx.x;            // grid 2048
    int b = bx >> 9, seg = (bx >> 4) & 31, dch = bx & 15;
    int d = dch * 64 + threadIdx.x;
    float cum = segsum[(b * 32 + seg) * 1024 + d];
    float sf = sfb[b * 1024 + d], sb = sbb[b * 1024 + d];
    size_t base = ((size_t)(b * 1024 + seg * 32)) * 1024 + d;
#pragma unroll 4
    for (int t = 0; t < 32; t++) {
        float prev = cum;
        cum += ew[base + (size_t)t * 1024];
        cf[base + (size_t)t * 1024] = fminf(fmaxf(cum - sf, -60.f), 60.f);
        cb[base + (size_t)t * 1024] = fminf(fmaxf(prev - sb, -60.f), 60.f);
    }
}

// ---------- bf16 MFMA GEMM core: C[4096][1024] = A @ W^T, async LDS staging ----------
// modes: 0 fp32 out, 1 silu fp32, 2 q-exp (O1=qf,O2=qb), 3 k-exp (O1=kf,O2=kb), 4 v-transpose (O1=vvt)
__device__ __forceinline__ void gemm_body(const unsigned short* __restrict__ A,
                                          const unsigned short* __restrict__ W,
                                          int m0, int n0, int mode,
                                          float* __restrict__ Cf,
                                          unsigned short* __restrict__ O1,
                                          unsigned short* __restrict__ O2,
                                          const float* __restrict__ cfp,
                                          const float* __restrict__ cbp,
                                          char* smem) {
    int tid = threadIdx.x;
    int w = tid >> 6, lane = tid & 63, l15 = lane & 15, qd = lane >> 4;
    int wm = w >> 1, wn = w & 1;
    fx4 acc[4][4];
#pragma unroll
    for (int mt = 0; mt < 4; mt++)
#pragma unroll
        for (int nt = 0; nt < 4; nt++)
#pragma unroll
            for (int r = 0; r < 4; r++) acc[mt][nt][r] = 0.f;
    unsigned short* sA = (unsigned short*)smem;            // [128][32]
    unsigned short* sB = (unsigned short*)(smem + 8192);   // [128][32]
    int rowA = tid >> 2, cA = tid & 3;
    for (int kb = 0; kb < 1024; kb += 32) {
        __syncthreads();
        GLD16(A + (size_t)(m0 + rowA) * 1024 + kb + cA * 8,      sA + w * 512);
        GLD16(A + (size_t)(m0 + 64 + rowA) * 1024 + kb + cA * 8, sA + 2048 + w * 512);
        GLD16(W + (size_t)(n0 + rowA) * 1024 + kb + cA * 8,      sB + w * 512);
        GLD16(W + (size_t)(n0 + 64 + rowA) * 1024 + kb + cA * 8, sB + 2048 + w * 512);
        __syncthreads();
        bh8 af[4], bfr[4];
#pragma unroll
        for (int mt = 0; mt < 4; mt++)
            af[mt] = *(const bh8*)(sA + (wm * 64 + mt * 16 + l15) * 32 + qd * 8);
#pragma unroll
        for (int nt = 0; nt < 4; nt++)
            bfr[nt] = *(const bh8*)(sB + (wn * 64 + nt * 16 + l15) * 32 + qd * 8);
#pragma unroll
        for (int mt = 0; mt < 4; mt++)
#pragma unroll
            for (int nt = 0; nt < 4; nt++)
                acc[mt][nt] = __builtin_amdgcn_mfma_f32_16x16x32_bf16(af[mt], bfr[nt], acc[mt][nt], 0, 0, 0);
    }
    int mb = m0 + wm * 64, nb = n0 + wn * 64;
    if (mode <= 1) {
#pragma unroll
        for (int mt = 0; mt < 4; mt++)
#pragma unroll
            for (int nt = 0; nt < 4; nt++) {
                fx4 s = acc[mt][nt];
#pragma unroll
                for (int r = 0; r < 4; r++) {
                    float v = s[r];
                    if (mode == 1) v = v / (1.f + __expf(-v));
                    Cf[(size_t)(mb + mt * 16 + qd * 4 + r) * 1024 + nb + nt * 16 + l15] = v;
                }
            }
    } else if (mode <= 3) {
        float s1 = (mode == 2) ? 1.f : -1.f;
#pragma unroll
        for (int mt = 0; mt < 4; mt++)
#pragma unroll
            for (int nt = 0; nt < 4; nt++) {
                fx4 s = acc[mt][nt];
#pragma unroll
                for (int r = 0; r < 4; r++) {
                    size_t idx = (size_t)(mb + mt * 16 + qd * 4 + r) * 1024 + nb + nt * 16 + l15;
                    float v = s[r];
                    O1[idx] = f2bf(v * __expf(s1 * cfp[idx]));
                    O2[idx] = f2bf(v * __expf(-s1 * cbp[idx]));
                }
            }
    } else {
        // transpose epilogue -> vvt[(b*1024 + d)][t]
        __syncthreads();
        unsigned short* T = (unsigned short*)smem;   // [128][136]
#pragma unroll
        for (int mt = 0; mt < 4; mt++)
#pragma unroll
            for (int nt = 0; nt < 4; nt++) {
                fx4 s = acc[mt][nt];
                int dl = wn * 64 + nt * 16 + l15;
                int tl = wm * 64 + mt * 16 + qd * 4;
                uint2 pk;
                pk.x = ((unsigned)f2bf(s[1]) << 16) | f2bf(s[0]);
                pk.y = ((unsigned)f2bf(s[3]) << 16) | f2bf(s[2]);
                *(uint2*)(T + dl * 136 + tl) = pk;
            }
        __syncthreads();
        int dl = tid >> 1, hf = tid & 1;
        int bq = m0 >> 10, t0 = m0 & 1023;
#pragma unroll
        for (int i = 0; i < 8; i++) {
            uint4 vv4 = *(const uint4*)(T + dl * 136 + hf * 64 + i * 8);
            *(uint4*)(O1 + (size_t)(bq * 1024 + n0 + dl) * 1024 + t0 + hf * 64 + i * 8) = vv4;
        }
    }
}

__global__ __launch_bounds__(256, 2) void k_gemm4(const unsigned short* __restrict__ xr16,
                                                  const unsigned short* __restrict__ xk16,
                                                  const unsigned short* __restrict__ xv16,
                                                  const unsigned short* __restrict__ xg16,
                                                  const unsigned short* __restrict__ Wrb,
                                                  const unsigned short* __restrict__ Wkb,
                                                  const unsigned short* __restrict__ Wvb,
                                                  const unsigned short* __restrict__ Wgb,
                                                  unsigned short* __restrict__ qf, unsigned short* __restrict__ qb,
                                                  unsigned short* __restrict__ kf, unsigned short* __restrict__ kb,
                                                  unsigned short* __restrict__ vvt,
                                                  float* __restrict__ gg,
                                                  const float* __restrict__ cf, const float* __restrict__ cb) {
    __shared__ __align__(16) char smem[34816];
    int m0 = (blockIdx.x >> 3) * 128, n0 = (blockIdx.x & 7) * 128;
    int y = blockIdx.y;
    if (y == 0)      gemm_body(xr16, Wrb, m0, n0, 2, nullptr, qf, qb, cf, cb, smem);
    else if (y == 1) gemm_body(xk16, Wkb, m0, n0, 3, nullptr, kf, kb, cf, cb, smem);
    else if (y == 2) gemm_body(xv16, Wvb, m0, n0, 4, nullptr, vvt, nullptr, nullptr, nullptr, smem);
    else             gemm_body(xg16, Wgb, m0, n0, 1, gg, nullptr, nullptr, nullptr, nullptr, smem);
}

__global__ __launch_bounds__(256, 2) void k_gemmo(const unsigned short* __restrict__ z16,
                                                  const unsigned short* __restrict__ Wob,
                                                  float* __restrict__ out) {
    __shared__ __align__(16) char smem[34816];
    gemm_body(z16, Wob, (blockIdx.x >> 3) * 128, (blockIdx.x & 7) * 128, 0, out,
              nullptr, nullptr, nullptr, nullptr, smem);
}

// ---------- attention: bidirectional LION via MFMA, no LDS, shfl S-redistribution ----------
__global__ __launch_bounds__(256, 4) void k_attn(const unsigned short* __restrict__ qf,
                                                 const unsigned short* __restrict__ qb,
                                                 const unsigned short* __restrict__ kf,
                                                 const unsigned short* __restrict__ kb,
                                                 const unsigned short* __restrict__ vvt,
                                                 float* __restrict__ y0,
                                                 float* __restrict__ y1) {
    int tid = threadIdx.x;
    int w = tid >> 6, lane = tid & 63, l15 = lane & 15, qd = lane >> 4;
    int bid = blockIdx.x;            // grid 1024 = 64 bh x 8 itile x 2 jhalf
    int jhalf = bid & 1;
    int ib = (bid >> 1) & 7;
    int bh = bid >> 4;
    int b = bh >> 4, h = bh & 15;
    int i0w = ib * 128 + w * 32;
    int bt0 = b * 1024;
    float* yout = jhalf ? y1 : y0;
    const unsigned short* vb0 = vvt + (size_t)(b * 1024 + h * 64 + l15) * 1024 + qd * 8;
    int nf = ((i0w + 31) >> 6) + 1;   // forward tiles: jt in [0, nf)
    int jb1 = i0w >> 6;               // backward tiles: jt in [jb1, 16)
    int srcA = l15 + ((lane & 16) << 1);   // l15 + 32*(qd&1)
    int srcB = srcA + 16;
    fx4 yacc[4][2];                   // [mt over d][nt over i]
#pragma unroll
    for (int mt = 0; mt < 4; mt++)
#pragma unroll
        for (int nt = 0; nt < 2; nt++)
#pragma unroll
            for (int r = 0; r < 4; r++) yacc[mt][nt][r] = 0.f;

    for (int phase = 0; phase < 2; phase++) {
        const unsigned short* Q = phase ? qb : qf;
        const unsigned short* K = phase ? kb : kf;
        bh8 qfr[2][2];
#pragma unroll
        for (int nt = 0; nt < 2; nt++)
#pragma unroll
            for (int ks = 0; ks < 2; ks++)
                qfr[nt][ks] = *(const bh8*)(Q + (size_t)(bt0 + i0w + nt * 16 + l15) * 1024
                                              + h * 64 + ks * 32 + qd * 8);
        int jt   = (phase == 0) ? jhalf : jb1 + ((jhalf + nf) & 1);
        int jend = (phase == 0) ? nf - 1 : 15;
        for (; jt <= jend; jt += 2) {
            int jb = jt * 64;
            bool needmask = (phase == 0) ? (jb + 63 > i0w) : (i0w + 31 >= jb);
            // S^T tile (64j x 32i): A = K rows(j), B = Q rows(i)
            fx4 sacc[4][2];
#pragma unroll
            for (int mt = 0; mt < 4; mt++)
#pragma unroll
                for (int nt = 0; nt < 2; nt++)
#pragma unroll
                    for (int r = 0; r < 4; r++) sacc[mt][nt][r] = 0.f;
#pragma unroll
            for (int ks = 0; ks < 2; ks++)
#pragma unroll
                for (int mt = 0; mt < 4; mt++) {
                    bh8 kfr = *(const bh8*)(K + (size_t)(bt0 + jb + mt * 16 + l15) * 1024
                                              + h * 64 + ks * 32 + qd * 8);
#pragma unroll
                    for (int nt = 0; nt < 2; nt++)
                        sacc[mt][nt] = __builtin_amdgcn_mfma_f32_16x16x32_bf16(kfr, qfr[nt][ks], sacc[mt][nt], 0, 0, 0);
                }
            // mask + pack bf16: pk[mt][nt] holds S^T[j = jb+mt*16+qd*4 + {0..3}][i = i0w+nt*16+l15]
            uint2 pk[4][2];
#pragma unroll
            for (int mt = 0; mt < 4; mt++)
#pragma unroll
                for (int nt = 0; nt < 2; nt++) {
                    fx4 s = sacc[mt][nt];
                    if (needmask) {
                        int ii = i0w + nt * 16 + l15;
                        int jj0 = jb + mt * 16 + qd * 4;
#pragma unroll
                        for (int r = 0; r < 4; r++) {
                            bool keep = (phase == 0) ? (ii >= jj0 + r) : (ii < jj0 + r);
                            if (!keep) s[r] = 0.f;
                        }
                    }
                    pk[mt][nt].x = ((unsigned)f2bf(s[1]) << 16) | f2bf(s[0]);
                    pk[mt][nt].y = ((unsigned)f2bf(s[3]) << 16) | f2bf(s[2]);
                }
            // y^T += V^T * S^T : A = V^T frag (global), B = S^T frag via shfl redistribution
#pragma unroll
            for (int ks2 = 0; ks2 < 2; ks2++) {
                bh8 av[4];
#pragma unroll
                for (int mt = 0; mt < 4; mt++)
                    av[mt] = *(const bh8*)(vb0 + (size_t)(mt * 16) * 1024 + jb + ks2 * 32);
#pragma unroll
                for (int nt = 0; nt < 2; nt++) {
                    int lox  = __shfl((int)pk[2 * ks2][nt].x,     srcA);
                    int hix  = __shfl((int)pk[2 * ks2 + 1][nt].x, srcA);
                    int loy  = __shfl((int)pk[2 * ks2][nt].y,     srcA);
                    int hiy  = __shfl((int)pk[2 * ks2 + 1][nt].y, srcA);
                    int lox2 = __shfl((int)pk[2 * ks2][nt].x,     srcB);
                    int hix2 = __shfl((int)pk[2 * ks2 + 1][nt].x, srcB);
                    int loy2 = __shfl((int)pk[2 * ks2][nt].y,     srcB);
                    int hiy2 = __shfl((int)pk[2 * ks2 + 1][nt].y, srcB);
                    union { int4 i; bh8 h; } cv;
                    cv.i.x = (qd & 2) ? hix  : lox;
                    cv.i.y = (qd & 2) ? hiy  : loy;
                    cv.i.z = (qd & 2) ? hix2 : lox2;
                    cv.i.w = (qd & 2) ? hiy2 : loy2;
#pragma unroll
                    for (int mt = 0; mt < 4; mt++)
                        yacc[mt][nt] = __builtin_amdgcn_mfma_f32_16x16x32_bf16(av[mt], cv.h, yacc[mt][nt], 0, 0, 0);
                }
            }
        }
    }
    // store y^T C-frags: i = col, d = row -> float4 along d
#pragma unroll
    for (int mt = 0; mt < 4; mt++)
#pragma unroll
        for (int nt = 0; nt < 2; nt++) {
            fx4 s = yacc[mt][nt];
            float4 o; o.x = s[0]; o.y = s[1]; o.z = s[2]; o.w = s[3];
            *(float4*)&yout[(size_t)(bt0 + i0w + nt * 16 + l15) * 1024 + h * 64 + mt * 16 + qd * 4] = o;
        }
}

// ---------- groupnorm * g -> bf16 z (sums the two attention partials) ----------
__global__ __launch_bounds__(256) void k_gn(const float* __restrict__ y0,
                                            const float* __restrict__ y1,
                                            const float* __restrict__ g,
                                            const float* __restrict__ lnw,
                                            const float* __restrict__ lnb,
                                            unsigned short* __restrict__ z16) {
    int tid = threadIdx.x;
    int lane = tid & 63;
    int wv = tid >> 6;
    int group = blockIdx.x * 4 + wv;     // grid 16384
    int tok = group >> 4, h = group & 15;
    int d = h * 64 + lane;
    size_t idx = (size_t)tok * 1024 + d;
    float val = y0[idx] + y1[idx];
    float s = val, s2 = val * val;
#pragma unroll
    for (int off = 32; off > 0; off >>= 1) {
        s  += __shfl_xor(s, off, 64);
        s2 += __shfl_xor(s2, off, 64);
    }
    float mu = s * (1.f / 64.f);
    float var = s2 * (1.f / 64.f) - mu * mu;
    float inv = rsqrtf(var + 6.4e-4f);
    float yn = (val - mu) * inv * lnw[d] + lnb[d];
    z16[idx] = f2bf(yn * g[idx]);
}

extern "C" void kernel_launch(void* const* d_in, const int* in_sizes, int n_in,
                              void* d_out, int out_size, void* d_ws, size_t ws_size,
                              hipStream_t stream) {
    const float* x     = (const float*)d_in[0];
    const float* maa_x = (const float*)d_in[1];
    const float* maa_w = (const float*)d_in[2];
    const float* maa_k = (const float*)d_in[3];
    const float* maa_v = (const float*)d_in[4];
    const float* maa_r = (const float*)d_in[5];
    const float* maa_g = (const float*)d_in[6];
    const float* w1    = (const float*)d_in[7];
    const float* w2    = (const float*)d_in[8];
    const float* tdec  = (const float*)d_in[9];
    const float* dw1   = (const float*)d_in[10];
    const float* dw2   = (const float*)d_in[11];
    const float* W_r   = (const float*)d_in[12];
    const float* W_k   = (const float*)d_in[13];
    const float* W_v   = (const float*)d_in[14];
    const float* W_g   = (const float*)d_in[15];
    const float* W_o   = (const float*)d_in[16];
    const float* lnw   = (const float*)d_in[17];
    const float* lnb   = (const float*)d_in[18];

    float* ws = (float*)d_ws;
    size_t o = 0;
    float* dech   = ws + o; o += 262144;
    float* segsum = ws + o; o += 131072;
    float* sfb    = ws + o; o += 4096;
    float* sbb    = ws + o; o += 4096;
    float* ew     = ws + o; o += 4194304;
    float* cf     = ws + o; o += 4194304;
    float* cb     = ws + o; o += 4194304;
    float* gg     = ws + o; o += 4194304;
    unsigned short* us = (unsigned short*)(ws + o);
    size_t u = 0;
    unsigned short* xmix16 = us + u; u += 4194304;
    unsigned short* xw16 = us + u; u += 4194304;
    unsigned short* xr16 = us + u; u += 4194304;   // also z16 after gemm4
    unsigned short* xk16 = us + u; u += 4194304;
    unsigned short* xv16 = us + u; u += 4194304;
    unsigned short* xg16 = us + u; u += 4194304;
    unsigned short* qf   = us + u; u += 4194304;
    unsigned short* qb   = us + u; u += 4194304;
    unsigned short* kf   = us + u; u += 4194304;
    unsigned short* kb   = us + u; u += 4194304;
    unsigned short* vvt  = us + u; u += 4194304;
    unsigned short* Wrb  = us + u; u += 1048576;
    unsigned short* Wkb  = us + u; u += 1048576;
    unsigned short* Wvb  = us + u; u += 1048576;
    unsigned short* Wgb  = us + u; u += 1048576;
    unsigned short* Wob  = us + u; u += 1048576;
    unsigned short* w1T  = us + u; u += 163840;
    unsigned short* dw1T = us + u; u += 65536;
    unsigned short* xxx16 = us + u; u += 655360;
    unsigned short* w2T16 = us + u; u += 163840;
    float* yb0 = cf;             // attention partials reuse cf/cb (dead after gemm4)
    float* yb1 = cb;
    unsigned short* z16 = xr16;  // dead after gemm4

    k_wconv<<<dim3(512, 5), 256, 0, stream>>>(W_r, W_k, W_v, W_g, W_o, Wrb, Wkb, Wvb, Wgb, Wob);
    k_tconv<<<640, 256, 0, stream>>>(w1, w1T, 160);
    k_tconv<<<256, 256, 0, stream>>>(dw1, dw1T, 64);
    k_w2t<<<dim3(4, 5), 256, 0, stream>>>(w2, w2T16);
    k_mixx<<<4096, 256, 0, stream>>>(x, maa_x, xmix16);
    k_xxx2<<<256, 64, 0, stream>>>(xmix16, w1T, xxx16);
    k_mmix<<<dim3(16, 32), 256, 0, stream>>>(x, xxx16, w2T16, maa_w, maa_k, maa_v, maa_r, maa_g,
                                             xw16, xk16, xv16, xr16, xg16);
    k_dec1m<<<256, 64, 0, stream>>>(xw16, dw1T, dech);
    k_dec2<<<512, 256, 0, stream>>>(dech, dw2, tdec, ew);
    k_scan1<<<2048, 64, 0, stream>>>(ew, segsum);
    k_scan2<<<64, 64, 0, stream>>>(ew, segsum, sfb, sbb);
    k_scan3<<<2048, 64, 0, stream>>>(ew, segsum, sfb, sbb, cf, cb);
    k_gemm4<<<dim3(256, 4), 256, 0, stream>>>(xr16, xk16, xv16, xg16, Wrb, Wkb, Wvb, Wgb,
                                              qf, qb, kf, kb, vvt, gg, cf, cb);
    k_attn<<<1024, 256, 0, stream>>>(qf, qb, kf, kb, vvt, yb0, yb1);
    k_gn<<<16384, 256, 0, stream>>>(yb0, yb1, gg, lnw, lnb, z16);
    k_gemmo<<<256, 256, 0, stream>>>(z16, Wob, (float*)d_out);
}